// Round 1
// baseline (442.661 us; speedup 1.0000x reference)
//
#include <hip/hip_runtime.h>

// VariationalGCNEncoder: N=50000 nodes, E=600000 edges, 128->128(relu)->2x64
// out = mu (50000x64) then logstd (50000x64), flat concat.
//
// Pipeline (all on `stream`, graph-capture safe):
//   memset counts/fillcnt -> count deg -> dis=rsqrt(deg+1) -> scan -> CSR fill
//   -> GEMM1 (x@W1 -> bufA) -> agg1 (relu(Â bufA + b1) -> bufB)
//   -> agg2 (Â bufB -> bufA) -> GEMM2 (bufA@[Wmu|Wls] + bias -> d_out split)

#define N_NODES 50000
#define N_EDGES 600000
#define MU_SIZE (N_NODES * 64)

__device__ __forceinline__ float bcastf(float v, int lane) {
  union { float f; int i; } u;
  u.f = v;
  u.i = __builtin_amdgcn_readlane(u.i, lane);
  return u.f;
}

__global__ __launch_bounds__(256) void count_kernel(const int* __restrict__ col,
                                                    int* __restrict__ counts, int e) {
  int i = blockIdx.x * 256 + threadIdx.x;
  if (i < e) atomicAdd(&counts[col[i]], 1);
}

__global__ __launch_bounds__(256) void dis_kernel(const int* __restrict__ counts,
                                                  float* __restrict__ dis, int n) {
  int i = blockIdx.x * 256 + threadIdx.x;
  if (i < n) dis[i] = rsqrtf((float)(counts[i] + 1));  // +1 self-loop, deg>=1 always
}

__global__ __launch_bounds__(1024) void scan_kernel(const int* __restrict__ counts,
                                                    int* __restrict__ offsets, int n) {
  __shared__ int sums[1024];
  int t = threadIdx.x;
  int chunk = (n + 1023) >> 10;
  int start = t * chunk;
  int end = min(start + chunk, n);
  int s = 0;
  for (int i = start; i < end; ++i) s += counts[i];
  sums[t] = s;
  __syncthreads();
  // Hillis-Steele inclusive scan over the 1024 partial sums
  for (int off = 1; off < 1024; off <<= 1) {
    int v = (t >= off) ? sums[t - off] : 0;
    __syncthreads();
    sums[t] += v;
    __syncthreads();
  }
  int prefix = (t == 0) ? 0 : sums[t - 1];
  for (int i = start; i < end; ++i) {
    offsets[i] = prefix;
    prefix += counts[i];
  }
  if (t == 1023) offsets[n] = sums[1023];
}

__global__ __launch_bounds__(256) void fill_kernel(const int* __restrict__ row,
                                                   const int* __restrict__ col,
                                                   const int* __restrict__ offsets,
                                                   int* __restrict__ fillcnt,
                                                   int* __restrict__ srcidx, int e) {
  int i = blockIdx.x * 256 + threadIdx.x;
  if (i < e) {
    int c = col[i];
    int pos = offsets[c] + atomicAdd(&fillcnt[c], 1);
    srcidx[pos] = row[i];
  }
}

// GEMM: Y[r][c] = sum_k X[r][k] * W[k][c], K=128, C=128.
// W staged in LDS as float2 pairs (W[j][c], W[j+64][c]); wave does 4 rows,
// lane l owns cols l and l+64; x broadcast via v_readlane (uniform j).
__global__ __launch_bounds__(256) void gemm1_kernel(const float* __restrict__ X,
                                                    const float* __restrict__ W,
                                                    float* __restrict__ Y, int ngroups) {
  __shared__ float2 lw[64 * 128];  // 64 KB
  for (int idx = threadIdx.x; idx < 64 * 128; idx += 256) {
    int j = idx >> 7, c = idx & 127;
    lw[idx] = make_float2(W[j * 128 + c], W[(j + 64) * 128 + c]);
  }
  __syncthreads();
  int wid = threadIdx.x >> 6, lane = threadIdx.x & 63;
  int gw = blockIdx.x * 4 + wid;
  int nw = gridDim.x * 4;
  for (int g = gw; g < ngroups; g += nw) {
    int r0 = g << 2;
    float xlo[4], xhi[4];
#pragma unroll
    for (int m = 0; m < 4; ++m) {
      xlo[m] = X[(r0 + m) * 128 + lane];
      xhi[m] = X[(r0 + m) * 128 + 64 + lane];
    }
    float acc0[4] = {0.f, 0.f, 0.f, 0.f};
    float acc1[4] = {0.f, 0.f, 0.f, 0.f};
#pragma unroll 8
    for (int j = 0; j < 64; ++j) {
      float2 wA = lw[j * 128 + lane];
      float2 wB = lw[j * 128 + 64 + lane];
#pragma unroll
      for (int m = 0; m < 4; ++m) {
        float a = bcastf(xlo[m], j);
        float b = bcastf(xhi[m], j);
        acc0[m] = fmaf(a, wA.x, acc0[m]);
        acc0[m] = fmaf(b, wA.y, acc0[m]);
        acc1[m] = fmaf(a, wB.x, acc1[m]);
        acc1[m] = fmaf(b, wB.y, acc1[m]);
      }
    }
#pragma unroll
    for (int m = 0; m < 4; ++m) {
      Y[(r0 + m) * 128 + lane] = acc0[m];
      Y[(r0 + m) * 128 + 64 + lane] = acc1[m];
    }
  }
}

// GEMM2: cols 0..63 = X@Wmu + bmu -> out[0..MU), cols 64..127 = X@Wls + bls
__global__ __launch_bounds__(256) void gemm2_kernel(const float* __restrict__ X,
                                                    const float* __restrict__ Wmu,
                                                    const float* __restrict__ Wls,
                                                    const float* __restrict__ bmu,
                                                    const float* __restrict__ bls,
                                                    float* __restrict__ out, int ngroups) {
  __shared__ float2 lw[64 * 128];  // 64 KB
  for (int idx = threadIdx.x; idx < 64 * 128; idx += 256) {
    int j = idx >> 7, c = idx & 127;
    float w0 = (c < 64) ? Wmu[j * 64 + c] : Wls[j * 64 + (c - 64)];
    float w1 = (c < 64) ? Wmu[(j + 64) * 64 + c] : Wls[(j + 64) * 64 + (c - 64)];
    lw[idx] = make_float2(w0, w1);
  }
  __syncthreads();
  int wid = threadIdx.x >> 6, lane = threadIdx.x & 63;
  int gw = blockIdx.x * 4 + wid;
  int nw = gridDim.x * 4;
  float bm = bmu[lane];
  float bl = bls[lane];
  for (int g = gw; g < ngroups; g += nw) {
    int r0 = g << 2;
    float xlo[4], xhi[4];
#pragma unroll
    for (int m = 0; m < 4; ++m) {
      xlo[m] = X[(r0 + m) * 128 + lane];
      xhi[m] = X[(r0 + m) * 128 + 64 + lane];
    }
    float acc0[4] = {0.f, 0.f, 0.f, 0.f};
    float acc1[4] = {0.f, 0.f, 0.f, 0.f};
#pragma unroll 8
    for (int j = 0; j < 64; ++j) {
      float2 wA = lw[j * 128 + lane];
      float2 wB = lw[j * 128 + 64 + lane];
#pragma unroll
      for (int m = 0; m < 4; ++m) {
        float a = bcastf(xlo[m], j);
        float b = bcastf(xhi[m], j);
        acc0[m] = fmaf(a, wA.x, acc0[m]);
        acc0[m] = fmaf(b, wA.y, acc0[m]);
        acc1[m] = fmaf(a, wB.x, acc1[m]);
        acc1[m] = fmaf(b, wB.y, acc1[m]);
      }
    }
#pragma unroll
    for (int m = 0; m < 4; ++m) {
      out[(r0 + m) * 64 + lane] = acc0[m] + bm;              // mu
      out[MU_SIZE + (r0 + m) * 64 + lane] = acc1[m] + bl;    // logstd
    }
  }
}

// One wave per node: out[i] = dis[i] * (H[i]*dis[i] + sum_e dis[src]*H[src]) (+b, relu)
template <bool BIAS_RELU>
__global__ __launch_bounds__(256) void aggregate_kernel(const float* __restrict__ H,
                                                        const int* __restrict__ offsets,
                                                        const int* __restrict__ srcidx,
                                                        const float* __restrict__ dis,
                                                        const float* __restrict__ bias,
                                                        float* __restrict__ out, int n) {
  int wid = threadIdx.x >> 6, lane = threadIdx.x & 63;
  int i = blockIdx.x * 4 + wid;
  if (i >= n) return;
  float di = dis[i];
  float acc0 = H[i * 128 + lane] * di;        // self-loop (norm = di*di, outer di applied at end)
  float acc1 = H[i * 128 + 64 + lane] * di;
  int beg = offsets[i], end = offsets[i + 1];
  for (int k = beg; k < end; ++k) {
    int r = srcidx[k];
    float dr = dis[r];
    acc0 = fmaf(dr, H[r * 128 + lane], acc0);
    acc1 = fmaf(dr, H[r * 128 + 64 + lane], acc1);
  }
  acc0 *= di;
  acc1 *= di;
  if (BIAS_RELU) {
    acc0 = fmaxf(acc0 + bias[lane], 0.f);
    acc1 = fmaxf(acc1 + bias[64 + lane], 0.f);
  }
  out[i * 128 + lane] = acc0;
  out[i * 128 + 64 + lane] = acc1;
}

extern "C" void kernel_launch(void* const* d_in, const int* in_sizes, int n_in,
                              void* d_out, int out_size, void* d_ws, size_t ws_size,
                              hipStream_t stream) {
  const float* x = (const float*)d_in[0];
  const int* ei = (const int*)d_in[1];  // [2][E] int32: row=src, col=dst
  const float* W1 = (const float*)d_in[2];
  const float* b1 = (const float*)d_in[3];
  const float* Wmu = (const float*)d_in[4];
  const float* bmu = (const float*)d_in[5];
  const float* Wls = (const float*)d_in[6];
  const float* bls = (const float*)d_in[7];
  float* out = (float*)d_out;

  const int* row = ei;
  const int* col = ei + N_EDGES;

  // workspace layout (~54.2 MB)
  float* bufA = (float*)d_ws;              // 6.4M f32
  float* bufB = bufA + 6400000;            // 6.4M f32
  float* dis = bufB + 6400000;             // 50000 f32
  int* counts = (int*)(dis + N_NODES);     // 50000 i32
  int* fillcnt = counts + N_NODES;         // 50000 i32
  int* offsets = fillcnt + N_NODES;        // 50001 i32
  int* srcidx = offsets + N_NODES + 1;     // 600000 i32

  hipMemsetAsync(counts, 0, 2 * N_NODES * sizeof(int), stream);  // counts + fillcnt

  int eb = (N_EDGES + 255) / 256;
  int nb = (N_NODES + 255) / 256;
  count_kernel<<<eb, 256, 0, stream>>>(col, counts, N_EDGES);
  dis_kernel<<<nb, 256, 0, stream>>>(counts, dis, N_NODES);
  scan_kernel<<<1, 1024, 0, stream>>>(counts, offsets, N_NODES);
  fill_kernel<<<eb, 256, 0, stream>>>(row, col, offsets, fillcnt, srcidx, N_EDGES);

  int ngroups = N_NODES / 4;  // 12500
  gemm1_kernel<<<1024, 256, 0, stream>>>(x, W1, bufA, ngroups);
  aggregate_kernel<true><<<N_NODES / 4, 256, 0, stream>>>(bufA, offsets, srcidx, dis, b1,
                                                          bufB, N_NODES);
  aggregate_kernel<false><<<N_NODES / 4, 256, 0, stream>>>(bufB, offsets, srcidx, dis,
                                                           nullptr, bufA, N_NODES);
  gemm2_kernel<<<1024, 256, 0, stream>>>(bufA, Wmu, Wls, bmu, bls, out, ngroups);
}

// Round 2
// 374.221 us; speedup vs baseline: 1.1829x; 1.1829x over previous
//
#include <hip/hip_runtime.h>

// VariationalGCNEncoder: N=50000 nodes, E=600000 edges, 128->128(relu)->2x64
// out = mu (50000x64) then logstd (50000x64), flat concat.
//
// R1: single-block scan_kernel was 78 us (1 CU, latency-bound,
// OccupancyPercent 0.15). Replaced with 200-block hierarchical scan
// (blocksum_dis_kernel + offsets_kernel); dis_kernel fused into blocksum.

#define N_NODES 50000
#define N_EDGES 600000
#define MU_SIZE (N_NODES * 64)
#define SCAN_BLOCKS 200
#define SCAN_CHUNK 250  // SCAN_BLOCKS * SCAN_CHUNK == N_NODES

__device__ __forceinline__ float bcastf(float v, int lane) {
  union { float f; int i; } u;
  u.f = v;
  u.i = __builtin_amdgcn_readlane(u.i, lane);
  return u.f;
}

__global__ __launch_bounds__(256) void count_kernel(const int* __restrict__ col,
                                                    int* __restrict__ counts, int e) {
  int i = blockIdx.x * 256 + threadIdx.x;
  if (i < e) atomicAdd(&counts[col[i]], 1);
}

// Per-block partial sums of counts (250 elems/block) + dis = rsqrt(deg+1)
__global__ __launch_bounds__(256) void blocksum_dis_kernel(const int* __restrict__ counts,
                                                           float* __restrict__ dis,
                                                           int* __restrict__ blocksums) {
  __shared__ int red[4];
  int b = blockIdx.x, t = threadIdx.x;
  int i = b * SCAN_CHUNK + t;
  int c = 0;
  if (t < SCAN_CHUNK) {
    c = counts[i];
    dis[i] = rsqrtf((float)(c + 1));  // +1 self-loop => deg >= 1 always
  }
  int s = c;
#pragma unroll
  for (int off = 32; off > 0; off >>= 1) s += __shfl_down(s, off, 64);
  if ((t & 63) == 0) red[t >> 6] = s;
  __syncthreads();
  if (t == 0) blocksums[b] = red[0] + red[1] + red[2] + red[3];
}

// Each block: scan the 200 blocksums in LDS for its exclusive base, then
// scan its own 250 counts and write exclusive offsets.
__global__ __launch_bounds__(256) void offsets_kernel(const int* __restrict__ counts,
                                                      const int* __restrict__ blocksums,
                                                      int* __restrict__ offsets) {
  __shared__ int sb[256];
  __shared__ int loc[256];
  int b = blockIdx.x, t = threadIdx.x;
  sb[t] = (t < SCAN_BLOCKS) ? blocksums[t] : 0;
  __syncthreads();
#pragma unroll
  for (int off = 1; off < 256; off <<= 1) {
    int v = (t >= off) ? sb[t - off] : 0;
    __syncthreads();
    sb[t] += v;
    __syncthreads();
  }
  int base = (b == 0) ? 0 : sb[b - 1];
  int i = b * SCAN_CHUNK + t;
  int c = (t < SCAN_CHUNK) ? counts[i] : 0;
  loc[t] = c;
  __syncthreads();
#pragma unroll
  for (int off = 1; off < 256; off <<= 1) {
    int v = (t >= off) ? loc[t - off] : 0;
    __syncthreads();
    loc[t] += v;
    __syncthreads();
  }
  if (t < SCAN_CHUNK) offsets[i] = base + loc[t] - c;  // exclusive
  if (b == SCAN_BLOCKS - 1 && t == SCAN_CHUNK - 1) offsets[N_NODES] = base + loc[t];
}

__global__ __launch_bounds__(256) void fill_kernel(const int* __restrict__ row,
                                                   const int* __restrict__ col,
                                                   const int* __restrict__ offsets,
                                                   int* __restrict__ fillcnt,
                                                   int* __restrict__ srcidx, int e) {
  int i = blockIdx.x * 256 + threadIdx.x;
  if (i < e) {
    int c = col[i];
    int pos = offsets[c] + atomicAdd(&fillcnt[c], 1);
    srcidx[pos] = row[i];
  }
}

// GEMM: Y[r][c] = sum_k X[r][k] * W[k][c], K=128, C=128.
// W staged in LDS as float2 pairs (W[j][c], W[j+64][c]); wave does 4 rows,
// lane l owns cols l and l+64; x broadcast via v_readlane (uniform j).
__global__ __launch_bounds__(256) void gemm1_kernel(const float* __restrict__ X,
                                                    const float* __restrict__ W,
                                                    float* __restrict__ Y, int ngroups) {
  __shared__ float2 lw[64 * 128];  // 64 KB
  for (int idx = threadIdx.x; idx < 64 * 128; idx += 256) {
    int j = idx >> 7, c = idx & 127;
    lw[idx] = make_float2(W[j * 128 + c], W[(j + 64) * 128 + c]);
  }
  __syncthreads();
  int wid = threadIdx.x >> 6, lane = threadIdx.x & 63;
  int gw = blockIdx.x * 4 + wid;
  int nw = gridDim.x * 4;
  for (int g = gw; g < ngroups; g += nw) {
    int r0 = g << 2;
    float xlo[4], xhi[4];
#pragma unroll
    for (int m = 0; m < 4; ++m) {
      xlo[m] = X[(r0 + m) * 128 + lane];
      xhi[m] = X[(r0 + m) * 128 + 64 + lane];
    }
    float acc0[4] = {0.f, 0.f, 0.f, 0.f};
    float acc1[4] = {0.f, 0.f, 0.f, 0.f};
#pragma unroll 8
    for (int j = 0; j < 64; ++j) {
      float2 wA = lw[j * 128 + lane];
      float2 wB = lw[j * 128 + 64 + lane];
#pragma unroll
      for (int m = 0; m < 4; ++m) {
        float a = bcastf(xlo[m], j);
        float b = bcastf(xhi[m], j);
        acc0[m] = fmaf(a, wA.x, acc0[m]);
        acc0[m] = fmaf(b, wA.y, acc0[m]);
        acc1[m] = fmaf(a, wB.x, acc1[m]);
        acc1[m] = fmaf(b, wB.y, acc1[m]);
      }
    }
#pragma unroll
    for (int m = 0; m < 4; ++m) {
      Y[(r0 + m) * 128 + lane] = acc0[m];
      Y[(r0 + m) * 128 + 64 + lane] = acc1[m];
    }
  }
}

// GEMM2: cols 0..63 = X@Wmu + bmu -> out[0..MU), cols 64..127 = X@Wls + bls
__global__ __launch_bounds__(256) void gemm2_kernel(const float* __restrict__ X,
                                                    const float* __restrict__ Wmu,
                                                    const float* __restrict__ Wls,
                                                    const float* __restrict__ bmu,
                                                    const float* __restrict__ bls,
                                                    float* __restrict__ out, int ngroups) {
  __shared__ float2 lw[64 * 128];  // 64 KB
  for (int idx = threadIdx.x; idx < 64 * 128; idx += 256) {
    int j = idx >> 7, c = idx & 127;
    float w0 = (c < 64) ? Wmu[j * 64 + c] : Wls[j * 64 + (c - 64)];
    float w1 = (c < 64) ? Wmu[(j + 64) * 64 + c] : Wls[(j + 64) * 64 + (c - 64)];
    lw[idx] = make_float2(w0, w1);
  }
  __syncthreads();
  int wid = threadIdx.x >> 6, lane = threadIdx.x & 63;
  int gw = blockIdx.x * 4 + wid;
  int nw = gridDim.x * 4;
  float bm = bmu[lane];
  float bl = bls[lane];
  for (int g = gw; g < ngroups; g += nw) {
    int r0 = g << 2;
    float xlo[4], xhi[4];
#pragma unroll
    for (int m = 0; m < 4; ++m) {
      xlo[m] = X[(r0 + m) * 128 + lane];
      xhi[m] = X[(r0 + m) * 128 + 64 + lane];
    }
    float acc0[4] = {0.f, 0.f, 0.f, 0.f};
    float acc1[4] = {0.f, 0.f, 0.f, 0.f};
#pragma unroll 8
    for (int j = 0; j < 64; ++j) {
      float2 wA = lw[j * 128 + lane];
      float2 wB = lw[j * 128 + 64 + lane];
#pragma unroll
      for (int m = 0; m < 4; ++m) {
        float a = bcastf(xlo[m], j);
        float b = bcastf(xhi[m], j);
        acc0[m] = fmaf(a, wA.x, acc0[m]);
        acc0[m] = fmaf(b, wA.y, acc0[m]);
        acc1[m] = fmaf(a, wB.x, acc1[m]);
        acc1[m] = fmaf(b, wB.y, acc1[m]);
      }
    }
#pragma unroll
    for (int m = 0; m < 4; ++m) {
      out[(r0 + m) * 64 + lane] = acc0[m] + bm;              // mu
      out[MU_SIZE + (r0 + m) * 64 + lane] = acc1[m] + bl;    // logstd
    }
  }
}

// One wave per node: out[i] = dis[i] * (H[i]*dis[i] + sum_e dis[src]*H[src]) (+b, relu)
template <bool BIAS_RELU>
__global__ __launch_bounds__(256) void aggregate_kernel(const float* __restrict__ H,
                                                        const int* __restrict__ offsets,
                                                        const int* __restrict__ srcidx,
                                                        const float* __restrict__ dis,
                                                        const float* __restrict__ bias,
                                                        float* __restrict__ out, int n) {
  int wid = threadIdx.x >> 6, lane = threadIdx.x & 63;
  int i = blockIdx.x * 4 + wid;
  if (i >= n) return;
  float di = dis[i];
  float acc0 = H[i * 128 + lane] * di;        // self-loop (norm = di*di, outer di applied at end)
  float acc1 = H[i * 128 + 64 + lane] * di;
  int beg = offsets[i], end = offsets[i + 1];
  for (int k = beg; k < end; ++k) {
    int r = srcidx[k];
    float dr = dis[r];
    acc0 = fmaf(dr, H[r * 128 + lane], acc0);
    acc1 = fmaf(dr, H[r * 128 + 64 + lane], acc1);
  }
  acc0 *= di;
  acc1 *= di;
  if (BIAS_RELU) {
    acc0 = fmaxf(acc0 + bias[lane], 0.f);
    acc1 = fmaxf(acc1 + bias[64 + lane], 0.f);
  }
  out[i * 128 + lane] = acc0;
  out[i * 128 + 64 + lane] = acc1;
}

extern "C" void kernel_launch(void* const* d_in, const int* in_sizes, int n_in,
                              void* d_out, int out_size, void* d_ws, size_t ws_size,
                              hipStream_t stream) {
  const float* x = (const float*)d_in[0];
  const int* ei = (const int*)d_in[1];  // [2][E] int32: row=src, col=dst
  const float* W1 = (const float*)d_in[2];
  const float* b1 = (const float*)d_in[3];
  const float* Wmu = (const float*)d_in[4];
  const float* bmu = (const float*)d_in[5];
  const float* Wls = (const float*)d_in[6];
  const float* bls = (const float*)d_in[7];
  float* out = (float*)d_out;

  const int* row = ei;
  const int* col = ei + N_EDGES;

  // workspace layout (~54.2 MB)
  float* bufA = (float*)d_ws;              // 6.4M f32
  float* bufB = bufA + 6400000;            // 6.4M f32
  float* dis = bufB + 6400000;             // 50000 f32
  int* counts = (int*)(dis + N_NODES);     // 50000 i32
  int* fillcnt = counts + N_NODES;         // 50000 i32
  int* offsets = fillcnt + N_NODES;        // 50001 i32
  int* srcidx = offsets + N_NODES + 1;     // 600000 i32
  int* blocksums = srcidx + N_EDGES;       // 200 i32

  hipMemsetAsync(counts, 0, 2 * N_NODES * sizeof(int), stream);  // counts + fillcnt

  int eb = (N_EDGES + 255) / 256;
  count_kernel<<<eb, 256, 0, stream>>>(col, counts, N_EDGES);
  blocksum_dis_kernel<<<SCAN_BLOCKS, 256, 0, stream>>>(counts, dis, blocksums);
  offsets_kernel<<<SCAN_BLOCKS, 256, 0, stream>>>(counts, blocksums, offsets);
  fill_kernel<<<eb, 256, 0, stream>>>(row, col, offsets, fillcnt, srcidx, N_EDGES);

  int ngroups = N_NODES / 4;  // 12500
  gemm1_kernel<<<1024, 256, 0, stream>>>(x, W1, bufA, ngroups);
  aggregate_kernel<true><<<N_NODES / 4, 256, 0, stream>>>(bufA, offsets, srcidx, dis, b1,
                                                          bufB, N_NODES);
  aggregate_kernel<false><<<N_NODES / 4, 256, 0, stream>>>(bufB, offsets, srcidx, dis,
                                                           nullptr, bufA, N_NODES);
  gemm2_kernel<<<1024, 256, 0, stream>>>(bufA, Wmu, Wls, bmu, bls, out, ngroups);
}

// Round 3
// 330.388 us; speedup vs baseline: 1.3398x; 1.1327x over previous
//
#include <hip/hip_runtime.h>

// VariationalGCNEncoder: N=50000 nodes, E=600000 edges, 128->128(relu)->2x64
// out = mu (50000x64) then logstd (50000x64), flat concat.
//
// R1: hierarchical scan (78us -> ~5us).
// R2: aggregate was latency-bound (69us, VALUBusy 14%, hbm 31%). Now:
//     float4 row gather (half-wave per edge), edge loop unrolled x2
//     (4 rows in flight/wave), and rows pre-scaled by dis in the producer
//     so the inner loop has no dis load/multiply.

#define N_NODES 50000
#define N_EDGES 600000
#define MU_SIZE (N_NODES * 64)
#define SCAN_BLOCKS 200
#define SCAN_CHUNK 250  // SCAN_BLOCKS * SCAN_CHUNK == N_NODES

__device__ __forceinline__ float bcastf(float v, int lane) {
  union { float f; int i; } u;
  u.f = v;
  u.i = __builtin_amdgcn_readlane(u.i, lane);
  return u.f;
}

__global__ __launch_bounds__(256) void count_kernel(const int* __restrict__ col,
                                                    int* __restrict__ counts, int e) {
  int i = blockIdx.x * 256 + threadIdx.x;
  if (i < e) atomicAdd(&counts[col[i]], 1);
}

// Per-block partial sums of counts (250 elems/block) + dis = rsqrt(deg+1)
__global__ __launch_bounds__(256) void blocksum_dis_kernel(const int* __restrict__ counts,
                                                           float* __restrict__ dis,
                                                           int* __restrict__ blocksums) {
  __shared__ int red[4];
  int b = blockIdx.x, t = threadIdx.x;
  int i = b * SCAN_CHUNK + t;
  int c = 0;
  if (t < SCAN_CHUNK) {
    c = counts[i];
    dis[i] = rsqrtf((float)(c + 1));  // +1 self-loop => deg >= 1 always
  }
  int s = c;
#pragma unroll
  for (int off = 32; off > 0; off >>= 1) s += __shfl_down(s, off, 64);
  if ((t & 63) == 0) red[t >> 6] = s;
  __syncthreads();
  if (t == 0) blocksums[b] = red[0] + red[1] + red[2] + red[3];
}

// Each block: scan the 200 blocksums in LDS for its exclusive base, then
// scan its own 250 counts and write exclusive offsets.
__global__ __launch_bounds__(256) void offsets_kernel(const int* __restrict__ counts,
                                                      const int* __restrict__ blocksums,
                                                      int* __restrict__ offsets) {
  __shared__ int sb[256];
  __shared__ int loc[256];
  int b = blockIdx.x, t = threadIdx.x;
  sb[t] = (t < SCAN_BLOCKS) ? blocksums[t] : 0;
  __syncthreads();
#pragma unroll
  for (int off = 1; off < 256; off <<= 1) {
    int v = (t >= off) ? sb[t - off] : 0;
    __syncthreads();
    sb[t] += v;
    __syncthreads();
  }
  int base = (b == 0) ? 0 : sb[b - 1];
  int i = b * SCAN_CHUNK + t;
  int c = (t < SCAN_CHUNK) ? counts[i] : 0;
  loc[t] = c;
  __syncthreads();
#pragma unroll
  for (int off = 1; off < 256; off <<= 1) {
    int v = (t >= off) ? loc[t - off] : 0;
    __syncthreads();
    loc[t] += v;
    __syncthreads();
  }
  if (t < SCAN_CHUNK) offsets[i] = base + loc[t] - c;  // exclusive
  if (b == SCAN_BLOCKS - 1 && t == SCAN_CHUNK - 1) offsets[N_NODES] = base + loc[t];
}

__global__ __launch_bounds__(256) void fill_kernel(const int* __restrict__ row,
                                                   const int* __restrict__ col,
                                                   const int* __restrict__ offsets,
                                                   int* __restrict__ fillcnt,
                                                   int* __restrict__ srcidx, int e) {
  int i = blockIdx.x * 256 + threadIdx.x;
  if (i < e) {
    int c = col[i];
    int pos = offsets[c] + atomicAdd(&fillcnt[c], 1);
    srcidx[pos] = row[i];
  }
}

// GEMM1: Y[r][c] = dis[r] * sum_k X[r][k] * W[k][c]   (pre-scaled output rows)
__global__ __launch_bounds__(256) void gemm1_kernel(const float* __restrict__ X,
                                                    const float* __restrict__ W,
                                                    const float* __restrict__ dis,
                                                    float* __restrict__ Y, int ngroups) {
  __shared__ float2 lw[64 * 128];  // 64 KB
  for (int idx = threadIdx.x; idx < 64 * 128; idx += 256) {
    int j = idx >> 7, c = idx & 127;
    lw[idx] = make_float2(W[j * 128 + c], W[(j + 64) * 128 + c]);
  }
  __syncthreads();
  int wid = threadIdx.x >> 6, lane = threadIdx.x & 63;
  int gw = blockIdx.x * 4 + wid;
  int nw = gridDim.x * 4;
  for (int g = gw; g < ngroups; g += nw) {
    int r0 = g << 2;
    float xlo[4], xhi[4], d[4];
#pragma unroll
    for (int m = 0; m < 4; ++m) {
      xlo[m] = X[(r0 + m) * 128 + lane];
      xhi[m] = X[(r0 + m) * 128 + 64 + lane];
      d[m] = dis[r0 + m];
    }
    float acc0[4] = {0.f, 0.f, 0.f, 0.f};
    float acc1[4] = {0.f, 0.f, 0.f, 0.f};
#pragma unroll 8
    for (int j = 0; j < 64; ++j) {
      float2 wA = lw[j * 128 + lane];
      float2 wB = lw[j * 128 + 64 + lane];
#pragma unroll
      for (int m = 0; m < 4; ++m) {
        float a = bcastf(xlo[m], j);
        float b = bcastf(xhi[m], j);
        acc0[m] = fmaf(a, wA.x, acc0[m]);
        acc0[m] = fmaf(b, wA.y, acc0[m]);
        acc1[m] = fmaf(a, wB.x, acc1[m]);
        acc1[m] = fmaf(b, wB.y, acc1[m]);
      }
    }
#pragma unroll
    for (int m = 0; m < 4; ++m) {
      Y[(r0 + m) * 128 + lane] = acc0[m] * d[m];
      Y[(r0 + m) * 128 + 64 + lane] = acc1[m] * d[m];
    }
  }
}

// GEMM2: cols 0..63 = X@Wmu + bmu -> out[0..MU), cols 64..127 = X@Wls + bls
__global__ __launch_bounds__(256) void gemm2_kernel(const float* __restrict__ X,
                                                    const float* __restrict__ Wmu,
                                                    const float* __restrict__ Wls,
                                                    const float* __restrict__ bmu,
                                                    const float* __restrict__ bls,
                                                    float* __restrict__ out, int ngroups) {
  __shared__ float2 lw[64 * 128];  // 64 KB
  for (int idx = threadIdx.x; idx < 64 * 128; idx += 256) {
    int j = idx >> 7, c = idx & 127;
    float w0 = (c < 64) ? Wmu[j * 64 + c] : Wls[j * 64 + (c - 64)];
    float w1 = (c < 64) ? Wmu[(j + 64) * 64 + c] : Wls[(j + 64) * 64 + (c - 64)];
    lw[idx] = make_float2(w0, w1);
  }
  __syncthreads();
  int wid = threadIdx.x >> 6, lane = threadIdx.x & 63;
  int gw = blockIdx.x * 4 + wid;
  int nw = gridDim.x * 4;
  float bm = bmu[lane];
  float bl = bls[lane];
  for (int g = gw; g < ngroups; g += nw) {
    int r0 = g << 2;
    float xlo[4], xhi[4];
#pragma unroll
    for (int m = 0; m < 4; ++m) {
      xlo[m] = X[(r0 + m) * 128 + lane];
      xhi[m] = X[(r0 + m) * 128 + 64 + lane];
    }
    float acc0[4] = {0.f, 0.f, 0.f, 0.f};
    float acc1[4] = {0.f, 0.f, 0.f, 0.f};
#pragma unroll 8
    for (int j = 0; j < 64; ++j) {
      float2 wA = lw[j * 128 + lane];
      float2 wB = lw[j * 128 + 64 + lane];
#pragma unroll
      for (int m = 0; m < 4; ++m) {
        float a = bcastf(xlo[m], j);
        float b = bcastf(xhi[m], j);
        acc0[m] = fmaf(a, wA.x, acc0[m]);
        acc0[m] = fmaf(b, wA.y, acc0[m]);
        acc1[m] = fmaf(a, wB.x, acc1[m]);
        acc1[m] = fmaf(b, wB.y, acc1[m]);
      }
    }
#pragma unroll
    for (int m = 0; m < 4; ++m) {
      out[(r0 + m) * 64 + lane] = acc0[m] + bm;              // mu
      out[MU_SIZE + (r0 + m) * 64 + lane] = acc1[m] + bl;    // logstd
    }
  }
}

// Input rows pre-scaled: Hs[i] = dis[i] * H[i].
// out[i] = di*(sum_{r in N(i)} Hs[r] + Hs[i])             (BIAS_RELU=false)
// out[i] = di*relu(di*(sum Hs[r] + Hs[i]) + b)            (BIAS_RELU=true, re-scaled
//          so the next aggregate can consume it directly)
// One wave per node; half-wave (32 lanes, float4) covers a full 512B row.
template <bool BIAS_RELU>
__global__ __launch_bounds__(256) void aggregate_kernel(const float* __restrict__ Hs,
                                                        const int* __restrict__ offsets,
                                                        const int* __restrict__ srcidx,
                                                        const float* __restrict__ dis,
                                                        const float* __restrict__ bias,
                                                        float* __restrict__ out, int n) {
  int wid = threadIdx.x >> 6, lane = threadIdx.x & 63;
  int half = lane >> 5, hl = lane & 31;
  int i = blockIdx.x * 4 + wid;
  if (i >= n) return;
  float di = dis[i];
  float4 selfv = ((const float4*)(Hs + (size_t)i * 128))[hl];
  int beg = offsets[i], end = offsets[i + 1];
  float4 acc = make_float4(0.f, 0.f, 0.f, 0.f);
  int k = beg + half;  // half 0 takes even slots, half 1 odd slots
  for (; k + 2 < end; k += 4) {  // 2 edges per half per iter -> 4 rows in flight
    int r0 = srcidx[k];
    int r1 = srcidx[k + 2];
    float4 v0 = ((const float4*)(Hs + (size_t)r0 * 128))[hl];
    float4 v1 = ((const float4*)(Hs + (size_t)r1 * 128))[hl];
    acc.x += v0.x + v1.x;
    acc.y += v0.y + v1.y;
    acc.z += v0.z + v1.z;
    acc.w += v0.w + v1.w;
  }
  if (k < end) {
    int r0 = srcidx[k];
    float4 v0 = ((const float4*)(Hs + (size_t)r0 * 128))[hl];
    acc.x += v0.x;
    acc.y += v0.y;
    acc.z += v0.z;
    acc.w += v0.w;
  }
  // combine the two halves (lane ^ 32)
  acc.x += __shfl(acc.x, lane ^ 32, 64);
  acc.y += __shfl(acc.y, lane ^ 32, 64);
  acc.z += __shfl(acc.z, lane ^ 32, 64);
  acc.w += __shfl(acc.w, lane ^ 32, 64);
  if (half == 0) {
    float sx = di * (acc.x + selfv.x);
    float sy = di * (acc.y + selfv.y);
    float sz = di * (acc.z + selfv.z);
    float sw = di * (acc.w + selfv.w);
    float4 o;
    if (BIAS_RELU) {
      float4 b = ((const float4*)bias)[hl];
      o.x = di * fmaxf(sx + b.x, 0.f);
      o.y = di * fmaxf(sy + b.y, 0.f);
      o.z = di * fmaxf(sz + b.z, 0.f);
      o.w = di * fmaxf(sw + b.w, 0.f);
    } else {
      o.x = sx; o.y = sy; o.z = sz; o.w = sw;
    }
    ((float4*)(out + (size_t)i * 128))[hl] = o;
  }
}

extern "C" void kernel_launch(void* const* d_in, const int* in_sizes, int n_in,
                              void* d_out, int out_size, void* d_ws, size_t ws_size,
                              hipStream_t stream) {
  const float* x = (const float*)d_in[0];
  const int* ei = (const int*)d_in[1];  // [2][E] int32: row=src, col=dst
  const float* W1 = (const float*)d_in[2];
  const float* b1 = (const float*)d_in[3];
  const float* Wmu = (const float*)d_in[4];
  const float* bmu = (const float*)d_in[5];
  const float* Wls = (const float*)d_in[6];
  const float* bls = (const float*)d_in[7];
  float* out = (float*)d_out;

  const int* row = ei;
  const int* col = ei + N_EDGES;

  // workspace layout (~54.2 MB)
  float* bufA = (float*)d_ws;              // 6.4M f32
  float* bufB = bufA + 6400000;            // 6.4M f32
  float* dis = bufB + 6400000;             // 50000 f32
  int* counts = (int*)(dis + N_NODES);     // 50000 i32
  int* fillcnt = counts + N_NODES;         // 50000 i32
  int* offsets = fillcnt + N_NODES;        // 50001 i32
  int* srcidx = offsets + N_NODES + 1;     // 600000 i32
  int* blocksums = srcidx + N_EDGES;       // 200 i32

  hipMemsetAsync(counts, 0, 2 * N_NODES * sizeof(int), stream);  // counts + fillcnt

  int eb = (N_EDGES + 255) / 256;
  count_kernel<<<eb, 256, 0, stream>>>(col, counts, N_EDGES);
  blocksum_dis_kernel<<<SCAN_BLOCKS, 256, 0, stream>>>(counts, dis, blocksums);
  offsets_kernel<<<SCAN_BLOCKS, 256, 0, stream>>>(counts, blocksums, offsets);
  fill_kernel<<<eb, 256, 0, stream>>>(row, col, offsets, fillcnt, srcidx, N_EDGES);

  int ngroups = N_NODES / 4;  // 12500
  gemm1_kernel<<<1024, 256, 0, stream>>>(x, W1, dis, bufA, ngroups);
  aggregate_kernel<true><<<N_NODES / 4, 256, 0, stream>>>(bufA, offsets, srcidx, dis, b1,
                                                          bufB, N_NODES);
  aggregate_kernel<false><<<N_NODES / 4, 256, 0, stream>>>(bufB, offsets, srcidx, dis,
                                                           nullptr, bufA, N_NODES);
  gemm2_kernel<<<1024, 256, 0, stream>>>(bufA, Wmu, Wls, bmu, bls, out, ngroups);
}

// Round 4
// 298.515 us; speedup vs baseline: 1.4829x; 1.1068x over previous
//
#include <hip/hip_runtime.h>

// VariationalGCNEncoder: N=50000 nodes, E=600000 edges, 128->128(relu)->2x64
// out = mu (50000x64) then logstd (50000x64), flat concat.
//
// R1: hierarchical scan (78us -> ~5us).
// R2: aggregate latency fix: float4 gather, half-wave/edge, dis pre-scaling.
// R3: GEMMs were 51.5us each (VALUBusy 60%, occ 17%, readlane-heavy inner
//     loop, 64KB LDS). Rewritten as classic LDS-tile GEMM: 64x128 block
//     tile, BK=32, XT transposed [32][68] + WC [32][128] (conflict-free),
//     4 rows x 8 cols per thread, 32 FMA / 3 ds_read_b128 per k, no readlane.

#define N_NODES 50000
#define N_EDGES 600000
#define MU_SIZE (N_NODES * 64)
#define SCAN_BLOCKS 200
#define SCAN_CHUNK 250  // SCAN_BLOCKS * SCAN_CHUNK == N_NODES
#define GM_BK 32

__global__ __launch_bounds__(256) void count_kernel(const int* __restrict__ col,
                                                    int* __restrict__ counts, int e) {
  int i = blockIdx.x * 256 + threadIdx.x;
  if (i < e) atomicAdd(&counts[col[i]], 1);
}

// Per-block partial sums of counts (250 elems/block) + dis = rsqrt(deg+1)
__global__ __launch_bounds__(256) void blocksum_dis_kernel(const int* __restrict__ counts,
                                                           float* __restrict__ dis,
                                                           int* __restrict__ blocksums) {
  __shared__ int red[4];
  int b = blockIdx.x, t = threadIdx.x;
  int i = b * SCAN_CHUNK + t;
  int c = 0;
  if (t < SCAN_CHUNK) {
    c = counts[i];
    dis[i] = rsqrtf((float)(c + 1));  // +1 self-loop => deg >= 1 always
  }
  int s = c;
#pragma unroll
  for (int off = 32; off > 0; off >>= 1) s += __shfl_down(s, off, 64);
  if ((t & 63) == 0) red[t >> 6] = s;
  __syncthreads();
  if (t == 0) blocksums[b] = red[0] + red[1] + red[2] + red[3];
}

// Each block: scan the 200 blocksums in LDS for its exclusive base, then
// scan its own 250 counts and write exclusive offsets.
__global__ __launch_bounds__(256) void offsets_kernel(const int* __restrict__ counts,
                                                      const int* __restrict__ blocksums,
                                                      int* __restrict__ offsets) {
  __shared__ int sb[256];
  __shared__ int loc[256];
  int b = blockIdx.x, t = threadIdx.x;
  sb[t] = (t < SCAN_BLOCKS) ? blocksums[t] : 0;
  __syncthreads();
#pragma unroll
  for (int off = 1; off < 256; off <<= 1) {
    int v = (t >= off) ? sb[t - off] : 0;
    __syncthreads();
    sb[t] += v;
    __syncthreads();
  }
  int base = (b == 0) ? 0 : sb[b - 1];
  int i = b * SCAN_CHUNK + t;
  int c = (t < SCAN_CHUNK) ? counts[i] : 0;
  loc[t] = c;
  __syncthreads();
#pragma unroll
  for (int off = 1; off < 256; off <<= 1) {
    int v = (t >= off) ? loc[t - off] : 0;
    __syncthreads();
    loc[t] += v;
    __syncthreads();
  }
  if (t < SCAN_CHUNK) offsets[i] = base + loc[t] - c;  // exclusive
  if (b == SCAN_BLOCKS - 1 && t == SCAN_CHUNK - 1) offsets[N_NODES] = base + loc[t];
}

__global__ __launch_bounds__(256) void fill_kernel(const int* __restrict__ row,
                                                   const int* __restrict__ col,
                                                   const int* __restrict__ offsets,
                                                   int* __restrict__ fillcnt,
                                                   int* __restrict__ srcidx, int e) {
  int i = blockIdx.x * 256 + threadIdx.x;
  if (i < e) {
    int c = col[i];
    int pos = offsets[c] + atomicAdd(&fillcnt[c], 1);
    srcidx[pos] = row[i];
  }
}

#define FMA4(acc, s, b)                \
  acc.x = fmaf(s, b.x, acc.x);         \
  acc.y = fmaf(s, b.y, acc.y);         \
  acc.z = fmaf(s, b.z, acc.z);         \
  acc.w = fmaf(s, b.w, acc.w)

// Tiled GEMM, M=50000, K=128, output 128 cols.
// SPLIT=false: Y[r][0..127] = dis[r] * (X @ Wa[128][128])          (gemm1)
// SPLIT=true : cols = [Wa|Wb] (each 128x64); Y0 = X@Wa + ba -> out[r*64+c],
//              Y1 = X@Wb + bb -> out[MU + r*64+c]                  (gemm2)
// Block: 64 rows x 128 cols; thread: rows r4..r4+3, cols {c4..c4+3, c4+64..c4+67}.
template <bool SPLIT>
__global__ __launch_bounds__(256) void gemm_kernel(const float* __restrict__ X,
                                                   const float* __restrict__ Wa,
                                                   const float* __restrict__ Wb,
                                                   const float* __restrict__ dis,
                                                   const float* __restrict__ ba,
                                                   const float* __restrict__ bb,
                                                   float* __restrict__ Y) {
  __shared__ float XT[GM_BK][68];   // transposed X tile, padded (2-way max)
  __shared__ float WC[GM_BK][128];  // W k-chunk, natural layout

  int t = threadIdx.x;
  int row0 = blockIdx.x * 64;
  // staging coords
  int sr = t >> 2;            // 0..63 tile row
  int sk = (t & 3) * 4;       // 0,4,8,12
  size_t gr = (size_t)min(row0 + sr, N_NODES - 1);
  // compute coords
  int r4 = (t >> 4) * 4;      // 0..60
  int c4 = (t & 15) * 4;      // 0..60

  float4 acc0[4], acc1[4];
#pragma unroll
  for (int m = 0; m < 4; ++m) {
    acc0[m] = make_float4(0.f, 0.f, 0.f, 0.f);
    acc1[m] = make_float4(0.f, 0.f, 0.f, 0.f);
  }

#pragma unroll
  for (int kc = 0; kc < 128 / GM_BK; ++kc) {
    int k0 = kc * GM_BK;
    if (kc) __syncthreads();
    // stage X tile transposed: XT[k][r]
    float4 x0 = *(const float4*)&X[gr * 128 + k0 + sk];
    float4 x1 = *(const float4*)&X[gr * 128 + k0 + 16 + sk];
    XT[sk + 0][sr] = x0.x;
    XT[sk + 1][sr] = x0.y;
    XT[sk + 2][sr] = x0.z;
    XT[sk + 3][sr] = x0.w;
    XT[16 + sk + 0][sr] = x1.x;
    XT[16 + sk + 1][sr] = x1.y;
    XT[16 + sk + 2][sr] = x1.z;
    XT[16 + sk + 3][sr] = x1.w;
    // stage W chunk: WC[k][0..127]
#pragma unroll
    for (int i = t; i < GM_BK * 32; i += 256) {
      int wr = i >> 5;
      int wc = (i & 31) * 4;
      float4 wv;
      if (!SPLIT) {
        wv = *(const float4*)&Wa[(size_t)(k0 + wr) * 128 + wc];
      } else {
        if (wc < 64)
          wv = *(const float4*)&Wa[(size_t)(k0 + wr) * 64 + wc];
        else
          wv = *(const float4*)&Wb[(size_t)(k0 + wr) * 64 + (wc - 64)];
      }
      *(float4*)&WC[wr][wc] = wv;
    }
    __syncthreads();
#pragma unroll 8
    for (int k = 0; k < GM_BK; ++k) {
      float4 a = *(const float4*)&XT[k][r4];
      float4 b0 = *(const float4*)&WC[k][c4];
      float4 b1 = *(const float4*)&WC[k][c4 + 64];
      FMA4(acc0[0], a.x, b0);
      FMA4(acc0[1], a.y, b0);
      FMA4(acc0[2], a.z, b0);
      FMA4(acc0[3], a.w, b0);
      FMA4(acc1[0], a.x, b1);
      FMA4(acc1[1], a.y, b1);
      FMA4(acc1[2], a.z, b1);
      FMA4(acc1[3], a.w, b1);
    }
  }

  if (!SPLIT) {
#pragma unroll
    for (int m = 0; m < 4; ++m) {
      int r = row0 + r4 + m;
      if (r < N_NODES) {
        float d = dis[r];
        float4 o0 = make_float4(acc0[m].x * d, acc0[m].y * d, acc0[m].z * d, acc0[m].w * d);
        float4 o1 = make_float4(acc1[m].x * d, acc1[m].y * d, acc1[m].z * d, acc1[m].w * d);
        *(float4*)&Y[(size_t)r * 128 + c4] = o0;
        *(float4*)&Y[(size_t)r * 128 + c4 + 64] = o1;
      }
    }
  } else {
    float4 bm = *(const float4*)&ba[c4];
    float4 bl = *(const float4*)&bb[c4];
#pragma unroll
    for (int m = 0; m < 4; ++m) {
      int r = row0 + r4 + m;
      if (r < N_NODES) {
        float4 o0 = make_float4(acc0[m].x + bm.x, acc0[m].y + bm.y, acc0[m].z + bm.z,
                                acc0[m].w + bm.w);
        float4 o1 = make_float4(acc1[m].x + bl.x, acc1[m].y + bl.y, acc1[m].z + bl.z,
                                acc1[m].w + bl.w);
        *(float4*)&Y[(size_t)r * 64 + c4] = o0;                 // mu
        *(float4*)&Y[MU_SIZE + (size_t)r * 64 + c4] = o1;       // logstd
      }
    }
  }
}

// Input rows pre-scaled: Hs[i] = dis[i] * H[i].
// BIAS_RELU=true:  out[i] = di * relu(di*(sum Hs[r] + Hs[i]) + b)  (re-scaled)
// BIAS_RELU=false: out[i] = di * (sum Hs[r] + Hs[i])
// One wave per node; half-wave (32 lanes, float4) covers a full 512B row.
template <bool BIAS_RELU>
__global__ __launch_bounds__(256) void aggregate_kernel(const float* __restrict__ Hs,
                                                        const int* __restrict__ offsets,
                                                        const int* __restrict__ srcidx,
                                                        const float* __restrict__ dis,
                                                        const float* __restrict__ bias,
                                                        float* __restrict__ out, int n) {
  int wid = threadIdx.x >> 6, lane = threadIdx.x & 63;
  int half = lane >> 5, hl = lane & 31;
  int i = blockIdx.x * 4 + wid;
  if (i >= n) return;
  float di = dis[i];
  float4 selfv = ((const float4*)(Hs + (size_t)i * 128))[hl];
  int beg = offsets[i], end = offsets[i + 1];
  float4 acc = make_float4(0.f, 0.f, 0.f, 0.f);
  int k = beg + half;  // half 0 takes even slots, half 1 odd slots
  for (; k + 2 < end; k += 4) {  // 2 edges per half per iter -> 4 rows in flight
    int r0 = srcidx[k];
    int r1 = srcidx[k + 2];
    float4 v0 = ((const float4*)(Hs + (size_t)r0 * 128))[hl];
    float4 v1 = ((const float4*)(Hs + (size_t)r1 * 128))[hl];
    acc.x += v0.x + v1.x;
    acc.y += v0.y + v1.y;
    acc.z += v0.z + v1.z;
    acc.w += v0.w + v1.w;
  }
  if (k < end) {
    int r0 = srcidx[k];
    float4 v0 = ((const float4*)(Hs + (size_t)r0 * 128))[hl];
    acc.x += v0.x;
    acc.y += v0.y;
    acc.z += v0.z;
    acc.w += v0.w;
  }
  // combine the two halves (lane ^ 32)
  acc.x += __shfl(acc.x, lane ^ 32, 64);
  acc.y += __shfl(acc.y, lane ^ 32, 64);
  acc.z += __shfl(acc.z, lane ^ 32, 64);
  acc.w += __shfl(acc.w, lane ^ 32, 64);
  if (half == 0) {
    float sx = di * (acc.x + selfv.x);
    float sy = di * (acc.y + selfv.y);
    float sz = di * (acc.z + selfv.z);
    float sw = di * (acc.w + selfv.w);
    float4 o;
    if (BIAS_RELU) {
      float4 b = ((const float4*)bias)[hl];
      o.x = di * fmaxf(sx + b.x, 0.f);
      o.y = di * fmaxf(sy + b.y, 0.f);
      o.z = di * fmaxf(sz + b.z, 0.f);
      o.w = di * fmaxf(sw + b.w, 0.f);
    } else {
      o.x = sx; o.y = sy; o.z = sz; o.w = sw;
    }
    ((float4*)(out + (size_t)i * 128))[hl] = o;
  }
}

extern "C" void kernel_launch(void* const* d_in, const int* in_sizes, int n_in,
                              void* d_out, int out_size, void* d_ws, size_t ws_size,
                              hipStream_t stream) {
  const float* x = (const float*)d_in[0];
  const int* ei = (const int*)d_in[1];  // [2][E] int32: row=src, col=dst
  const float* W1 = (const float*)d_in[2];
  const float* b1 = (const float*)d_in[3];
  const float* Wmu = (const float*)d_in[4];
  const float* bmu = (const float*)d_in[5];
  const float* Wls = (const float*)d_in[6];
  const float* bls = (const float*)d_in[7];
  float* out = (float*)d_out;

  const int* row = ei;
  const int* col = ei + N_EDGES;

  // workspace layout (~54.2 MB)
  float* bufA = (float*)d_ws;              // 6.4M f32
  float* bufB = bufA + 6400000;            // 6.4M f32
  float* dis = bufB + 6400000;             // 50000 f32
  int* counts = (int*)(dis + N_NODES);     // 50000 i32
  int* fillcnt = counts + N_NODES;         // 50000 i32
  int* offsets = fillcnt + N_NODES;        // 50001 i32
  int* srcidx = offsets + N_NODES + 1;     // 600000 i32
  int* blocksums = srcidx + N_EDGES;       // 200 i32

  hipMemsetAsync(counts, 0, 2 * N_NODES * sizeof(int), stream);  // counts + fillcnt

  int eb = (N_EDGES + 255) / 256;
  count_kernel<<<eb, 256, 0, stream>>>(col, counts, N_EDGES);
  blocksum_dis_kernel<<<SCAN_BLOCKS, 256, 0, stream>>>(counts, dis, blocksums);
  offsets_kernel<<<SCAN_BLOCKS, 256, 0, stream>>>(counts, blocksums, offsets);
  fill_kernel<<<eb, 256, 0, stream>>>(row, col, offsets, fillcnt, srcidx, N_EDGES);

  int gb = (N_NODES + 63) / 64;  // 782
  gemm_kernel<false><<<gb, 256, 0, stream>>>(x, W1, nullptr, dis, nullptr, nullptr, bufA);
  aggregate_kernel<true><<<N_NODES / 4, 256, 0, stream>>>(bufA, offsets, srcidx, dis, b1,
                                                          bufB, N_NODES);
  aggregate_kernel<false><<<N_NODES / 4, 256, 0, stream>>>(bufB, offsets, srcidx, dis,
                                                           nullptr, bufA, N_NODES);
  gemm_kernel<true><<<gb, 256, 0, stream>>>(bufA, Wmu, Wls, nullptr, bmu, bls, out);
}

// Round 5
// 256.576 us; speedup vs baseline: 1.7253x; 1.1635x over previous
//
#include <hip/hip_runtime.h>
#include <hip/hip_fp16.h>

// VariationalGCNEncoder: N=50000 nodes, E=600000 edges, 128->128(relu)->2x64
// out = mu (50000x64) then logstd (50000x64), flat concat.
//
// R1: hierarchical scan (78us -> ~5us).
// R2: aggregate latency fix: float4 gather, half-wave/edge, dis pre-scaling.
// R3: LDS-tile GEMM (51.5us -> <46us each).
// R4: aggregates 46us each, FETCH 143MB (512B fp32 row per edge, L2-miss
//     bound). Aggregation operand now stored fp16 (fp32 accumulate): row =
//     256B -> quarter-wave gather (16 lanes x float4 = 8 halves), 8 rows in
//     flight per wave. agg2 still emits fp32 for gemm2.

#define N_NODES 50000
#define N_EDGES 600000
#define MU_SIZE (N_NODES * 64)
#define SCAN_BLOCKS 200
#define SCAN_CHUNK 250  // SCAN_BLOCKS * SCAN_CHUNK == N_NODES
#define GM_BK 32

union H4 { __half2 h2[2]; float2 f2; };
union H8 { __half2 h2[4]; float4 f4; };

__global__ __launch_bounds__(256) void count_kernel(const int* __restrict__ col,
                                                    int* __restrict__ counts, int e) {
  int i = blockIdx.x * 256 + threadIdx.x;
  if (i < e) atomicAdd(&counts[col[i]], 1);
}

// Per-block partial sums of counts (250 elems/block) + dis = rsqrt(deg+1)
__global__ __launch_bounds__(256) void blocksum_dis_kernel(const int* __restrict__ counts,
                                                           float* __restrict__ dis,
                                                           int* __restrict__ blocksums) {
  __shared__ int red[4];
  int b = blockIdx.x, t = threadIdx.x;
  int i = b * SCAN_CHUNK + t;
  int c = 0;
  if (t < SCAN_CHUNK) {
    c = counts[i];
    dis[i] = rsqrtf((float)(c + 1));  // +1 self-loop => deg >= 1 always
  }
  int s = c;
#pragma unroll
  for (int off = 32; off > 0; off >>= 1) s += __shfl_down(s, off, 64);
  if ((t & 63) == 0) red[t >> 6] = s;
  __syncthreads();
  if (t == 0) blocksums[b] = red[0] + red[1] + red[2] + red[3];
}

// Each block: scan the 200 blocksums in LDS for its exclusive base, then
// scan its own 250 counts and write exclusive offsets.
__global__ __launch_bounds__(256) void offsets_kernel(const int* __restrict__ counts,
                                                      const int* __restrict__ blocksums,
                                                      int* __restrict__ offsets) {
  __shared__ int sb[256];
  __shared__ int loc[256];
  int b = blockIdx.x, t = threadIdx.x;
  sb[t] = (t < SCAN_BLOCKS) ? blocksums[t] : 0;
  __syncthreads();
#pragma unroll
  for (int off = 1; off < 256; off <<= 1) {
    int v = (t >= off) ? sb[t - off] : 0;
    __syncthreads();
    sb[t] += v;
    __syncthreads();
  }
  int base = (b == 0) ? 0 : sb[b - 1];
  int i = b * SCAN_CHUNK + t;
  int c = (t < SCAN_CHUNK) ? counts[i] : 0;
  loc[t] = c;
  __syncthreads();
#pragma unroll
  for (int off = 1; off < 256; off <<= 1) {
    int v = (t >= off) ? loc[t - off] : 0;
    __syncthreads();
    loc[t] += v;
    __syncthreads();
  }
  if (t < SCAN_CHUNK) offsets[i] = base + loc[t] - c;  // exclusive
  if (b == SCAN_BLOCKS - 1 && t == SCAN_CHUNK - 1) offsets[N_NODES] = base + loc[t];
}

__global__ __launch_bounds__(256) void fill_kernel(const int* __restrict__ row,
                                                   const int* __restrict__ col,
                                                   const int* __restrict__ offsets,
                                                   int* __restrict__ fillcnt,
                                                   int* __restrict__ srcidx, int e) {
  int i = blockIdx.x * 256 + threadIdx.x;
  if (i < e) {
    int c = col[i];
    int pos = offsets[c] + atomicAdd(&fillcnt[c], 1);
    srcidx[pos] = row[i];
  }
}

#define FMA4(acc, s, b)                \
  acc.x = fmaf(s, b.x, acc.x);         \
  acc.y = fmaf(s, b.y, acc.y);         \
  acc.z = fmaf(s, b.z, acc.z);         \
  acc.w = fmaf(s, b.w, acc.w)

// Tiled GEMM, M=50000, K=128, output 128 cols.
// SPLIT=false: Yh[r][0..127] = fp16( dis[r] * (X @ Wa[128][128]) )   (gemm1)
// SPLIT=true : cols = [Wa|Wb] (each 128x64); Yf0 = X@Wa + ba -> out[r*64+c],
//              Yf1 = X@Wb + bb -> out[MU + r*64+c]                   (gemm2)
// Block: 64 rows x 128 cols; thread: rows r4..r4+3, cols {c4..c4+3, c4+64..c4+67}.
template <bool SPLIT>
__global__ __launch_bounds__(256) void gemm_kernel(const float* __restrict__ X,
                                                   const float* __restrict__ Wa,
                                                   const float* __restrict__ Wb,
                                                   const float* __restrict__ dis,
                                                   const float* __restrict__ ba,
                                                   const float* __restrict__ bb,
                                                   __half* __restrict__ Yh,
                                                   float* __restrict__ Yf) {
  __shared__ float XT[GM_BK][68];   // transposed X tile, padded (2-way max)
  __shared__ float WC[GM_BK][128];  // W k-chunk, natural layout

  int t = threadIdx.x;
  int row0 = blockIdx.x * 64;
  // staging coords
  int sr = t >> 2;            // 0..63 tile row
  int sk = (t & 3) * 4;       // 0,4,8,12
  size_t gr = (size_t)min(row0 + sr, N_NODES - 1);
  // compute coords
  int r4 = (t >> 4) * 4;      // 0..60
  int c4 = (t & 15) * 4;      // 0..60

  float4 acc0[4], acc1[4];
#pragma unroll
  for (int m = 0; m < 4; ++m) {
    acc0[m] = make_float4(0.f, 0.f, 0.f, 0.f);
    acc1[m] = make_float4(0.f, 0.f, 0.f, 0.f);
  }

#pragma unroll
  for (int kc = 0; kc < 128 / GM_BK; ++kc) {
    int k0 = kc * GM_BK;
    if (kc) __syncthreads();
    // stage X tile transposed: XT[k][r]
    float4 x0 = *(const float4*)&X[gr * 128 + k0 + sk];
    float4 x1 = *(const float4*)&X[gr * 128 + k0 + 16 + sk];
    XT[sk + 0][sr] = x0.x;
    XT[sk + 1][sr] = x0.y;
    XT[sk + 2][sr] = x0.z;
    XT[sk + 3][sr] = x0.w;
    XT[16 + sk + 0][sr] = x1.x;
    XT[16 + sk + 1][sr] = x1.y;
    XT[16 + sk + 2][sr] = x1.z;
    XT[16 + sk + 3][sr] = x1.w;
    // stage W chunk: WC[k][0..127]
#pragma unroll
    for (int i = t; i < GM_BK * 32; i += 256) {
      int wr = i >> 5;
      int wc = (i & 31) * 4;
      float4 wv;
      if (!SPLIT) {
        wv = *(const float4*)&Wa[(size_t)(k0 + wr) * 128 + wc];
      } else {
        if (wc < 64)
          wv = *(const float4*)&Wa[(size_t)(k0 + wr) * 64 + wc];
        else
          wv = *(const float4*)&Wb[(size_t)(k0 + wr) * 64 + (wc - 64)];
      }
      *(float4*)&WC[wr][wc] = wv;
    }
    __syncthreads();
#pragma unroll 8
    for (int k = 0; k < GM_BK; ++k) {
      float4 a = *(const float4*)&XT[k][r4];
      float4 b0 = *(const float4*)&WC[k][c4];
      float4 b1 = *(const float4*)&WC[k][c4 + 64];
      FMA4(acc0[0], a.x, b0);
      FMA4(acc0[1], a.y, b0);
      FMA4(acc0[2], a.z, b0);
      FMA4(acc0[3], a.w, b0);
      FMA4(acc1[0], a.x, b1);
      FMA4(acc1[1], a.y, b1);
      FMA4(acc1[2], a.z, b1);
      FMA4(acc1[3], a.w, b1);
    }
  }

  if (!SPLIT) {
#pragma unroll
    for (int m = 0; m < 4; ++m) {
      int r = row0 + r4 + m;
      if (r < N_NODES) {
        float d = dis[r];
        H4 u0, u1;
        u0.h2[0] = __float22half2_rn(make_float2(acc0[m].x * d, acc0[m].y * d));
        u0.h2[1] = __float22half2_rn(make_float2(acc0[m].z * d, acc0[m].w * d));
        u1.h2[0] = __float22half2_rn(make_float2(acc1[m].x * d, acc1[m].y * d));
        u1.h2[1] = __float22half2_rn(make_float2(acc1[m].z * d, acc1[m].w * d));
        *(float2*)&Yh[(size_t)r * 128 + c4] = u0.f2;
        *(float2*)&Yh[(size_t)r * 128 + c4 + 64] = u1.f2;
      }
    }
  } else {
    float4 bm = *(const float4*)&ba[c4];
    float4 bl = *(const float4*)&bb[c4];
#pragma unroll
    for (int m = 0; m < 4; ++m) {
      int r = row0 + r4 + m;
      if (r < N_NODES) {
        float4 o0 = make_float4(acc0[m].x + bm.x, acc0[m].y + bm.y, acc0[m].z + bm.z,
                                acc0[m].w + bm.w);
        float4 o1 = make_float4(acc1[m].x + bl.x, acc1[m].y + bl.y, acc1[m].z + bl.z,
                                acc1[m].w + bl.w);
        *(float4*)&Yf[(size_t)r * 64 + c4] = o0;                 // mu
        *(float4*)&Yf[MU_SIZE + (size_t)r * 64 + c4] = o1;       // logstd
      }
    }
  }
}

// Input rows fp16, pre-scaled: Hs[i] = fp16(dis[i] * H[i]). fp32 accumulate.
// BIAS_RELU=true:  outH[i] = fp16( di * relu(di*(sum Hs[r] + Hs[i]) + b) )
// BIAS_RELU=false: outF[i] = di * (sum Hs[r] + Hs[i])          (fp32, gemm2 input)
// One wave per node; quarter-wave (16 lanes x float4 = 8 halves) covers a
// 256B row; 4 edge slots/wave, unrolled x2 -> 8 gathers in flight.
template <bool BIAS_RELU>
__global__ __launch_bounds__(256) void aggregate_kernel(const __half* __restrict__ Hs,
                                                        const int* __restrict__ offsets,
                                                        const int* __restrict__ srcidx,
                                                        const float* __restrict__ dis,
                                                        const float* __restrict__ bias,
                                                        __half* __restrict__ outH,
                                                        float* __restrict__ outF, int n) {
  int wid = threadIdx.x >> 6, lane = threadIdx.x & 63;
  int q = lane >> 4, ql = lane & 15;
  int i = blockIdx.x * 4 + wid;
  if (i >= n) return;
  float di = dis[i];
  float4 selfv = ((const float4*)(Hs + (size_t)i * 128))[ql];
  float acc[8] = {0.f, 0.f, 0.f, 0.f, 0.f, 0.f, 0.f, 0.f};
  int beg = offsets[i], end = offsets[i + 1];
  int k = beg + q;  // quarter q owns slots beg+q, beg+q+4, ...
  for (; k + 4 < end; k += 8) {  // 2 edges per quarter per iter
    int r0 = srcidx[k];
    int r1 = srcidx[k + 4];
    float4 v0 = ((const float4*)(Hs + (size_t)r0 * 128))[ql];
    float4 v1 = ((const float4*)(Hs + (size_t)r1 * 128))[ql];
    const __half2* a0 = (const __half2*)&v0;
    const __half2* a1 = (const __half2*)&v1;
#pragma unroll
    for (int j = 0; j < 4; ++j) {
      float2 f0 = __half22float2(a0[j]);
      float2 f1 = __half22float2(a1[j]);
      acc[2 * j] += f0.x + f1.x;
      acc[2 * j + 1] += f0.y + f1.y;
    }
  }
  if (k < end) {
    int r0 = srcidx[k];
    float4 v0 = ((const float4*)(Hs + (size_t)r0 * 128))[ql];
    const __half2* a0 = (const __half2*)&v0;
#pragma unroll
    for (int j = 0; j < 4; ++j) {
      float2 f0 = __half22float2(a0[j]);
      acc[2 * j] += f0.x;
      acc[2 * j + 1] += f0.y;
    }
  }
  // combine the four quarters
#pragma unroll
  for (int j = 0; j < 8; ++j) {
    acc[j] += __shfl(acc[j], lane ^ 16, 64);
    acc[j] += __shfl(acc[j], lane ^ 32, 64);
  }
  if (q == 0) {
    const __half2* sh = (const __half2*)&selfv;
    float s[8];
#pragma unroll
    for (int j = 0; j < 4; ++j) {
      float2 f = __half22float2(sh[j]);
      s[2 * j] = di * (acc[2 * j] + f.x);
      s[2 * j + 1] = di * (acc[2 * j + 1] + f.y);
    }
    if (BIAS_RELU) {
      float4 b0 = ((const float4*)bias)[2 * ql];
      float4 b1 = ((const float4*)bias)[2 * ql + 1];
      H8 u;
      u.h2[0] = __float22half2_rn(
          make_float2(di * fmaxf(s[0] + b0.x, 0.f), di * fmaxf(s[1] + b0.y, 0.f)));
      u.h2[1] = __float22half2_rn(
          make_float2(di * fmaxf(s[2] + b0.z, 0.f), di * fmaxf(s[3] + b0.w, 0.f)));
      u.h2[2] = __float22half2_rn(
          make_float2(di * fmaxf(s[4] + b1.x, 0.f), di * fmaxf(s[5] + b1.y, 0.f)));
      u.h2[3] = __float22half2_rn(
          make_float2(di * fmaxf(s[6] + b1.z, 0.f), di * fmaxf(s[7] + b1.w, 0.f)));
      ((float4*)(outH + (size_t)i * 128))[ql] = u.f4;
    } else {
      ((float4*)(outF + (size_t)i * 128))[2 * ql] = make_float4(s[0], s[1], s[2], s[3]);
      ((float4*)(outF + (size_t)i * 128))[2 * ql + 1] = make_float4(s[4], s[5], s[6], s[7]);
    }
  }
}

extern "C" void kernel_launch(void* const* d_in, const int* in_sizes, int n_in,
                              void* d_out, int out_size, void* d_ws, size_t ws_size,
                              hipStream_t stream) {
  const float* x = (const float*)d_in[0];
  const int* ei = (const int*)d_in[1];  // [2][E] int32: row=src, col=dst
  const float* W1 = (const float*)d_in[2];
  const float* b1 = (const float*)d_in[3];
  const float* Wmu = (const float*)d_in[4];
  const float* bmu = (const float*)d_in[5];
  const float* Wls = (const float*)d_in[6];
  const float* bls = (const float*)d_in[7];
  float* out = (float*)d_out;

  const int* row = ei;
  const int* col = ei + N_EDGES;

  // workspace layout (~54.1 MB)
  float* bufA = (float*)d_ws;                  // 6.4M f32 (gemm2 input)
  __half* bufAh = (__half*)(bufA + 6400000);   // 6.4M f16 (gemm1 out, agg1 in)
  __half* bufBh = bufAh + 6400000;             // 6.4M f16 (agg1 out, agg2 in)
  float* dis = (float*)(bufBh + 6400000);      // 50000 f32
  int* counts = (int*)(dis + N_NODES);         // 50000 i32
  int* fillcnt = counts + N_NODES;             // 50000 i32
  int* offsets = fillcnt + N_NODES;            // 50001 i32
  int* srcidx = offsets + N_NODES + 1;         // 600000 i32
  int* blocksums = srcidx + N_EDGES;           // 200 i32

  hipMemsetAsync(counts, 0, 2 * N_NODES * sizeof(int), stream);  // counts + fillcnt

  int eb = (N_EDGES + 255) / 256;
  count_kernel<<<eb, 256, 0, stream>>>(col, counts, N_EDGES);
  blocksum_dis_kernel<<<SCAN_BLOCKS, 256, 0, stream>>>(counts, dis, blocksums);
  offsets_kernel<<<SCAN_BLOCKS, 256, 0, stream>>>(counts, blocksums, offsets);
  fill_kernel<<<eb, 256, 0, stream>>>(row, col, offsets, fillcnt, srcidx, N_EDGES);

  int gb = (N_NODES + 63) / 64;  // 782
  gemm_kernel<false><<<gb, 256, 0, stream>>>(x, W1, nullptr, dis, nullptr, nullptr,
                                             bufAh, nullptr);
  aggregate_kernel<true><<<N_NODES / 4, 256, 0, stream>>>(bufAh, offsets, srcidx, dis, b1,
                                                          bufBh, nullptr, N_NODES);
  aggregate_kernel<false><<<N_NODES / 4, 256, 0, stream>>>(bufBh, offsets, srcidx, dis,
                                                           nullptr, nullptr, bufA, N_NODES);
  gemm_kernel<true><<<gb, 256, 0, stream>>>(bufA, Wmu, Wls, nullptr, bmu, bls, nullptr, out);
}

// Round 6
// 230.462 us; speedup vs baseline: 1.9208x; 1.1133x over previous
//
#include <hip/hip_runtime.h>
#include <hip/hip_fp16.h>

// VariationalGCNEncoder: N=50000 nodes, E=600000 edges, 128->128(relu)->2x64
// out = mu (50000x64) then logstd (50000x64), flat concat.
//
// R1: hierarchical scan (78us -> ~5us).
// R2: aggregate latency fix: float4 gather, half-wave/edge, dis pre-scaling.
// R3: LDS-tile VALU GEMM (51.5 -> ~38us each).
// R4: fp16 aggregation operand (aggregates 46 -> ~25us each).
// R5: GEMMs were still VALU-bound (~35-40us each at ~20% of 157TF). Now
//     MFMA fp16: v_mfma_f32_16x16x32_f16, whole W in LDS as transposed fp16
//     WT[n][k] stride 136 (even bank use for ds_read_b128), wave = 16 rows x
//     128 cols = 8 tiles x 4 K-chunks = 32 MFMA. agg2 emits fp16 for gemm2.

#define N_NODES 50000
#define N_EDGES 600000
#define MU_SIZE (N_NODES * 64)
#define SCAN_BLOCKS 200
#define SCAN_CHUNK 250  // SCAN_BLOCKS * SCAN_CHUNK == N_NODES
#define WT_S 136        // LDS row stride (halves) for WT[n][k]

typedef _Float16 half8 __attribute__((ext_vector_type(8)));
typedef float floatx4 __attribute__((ext_vector_type(4)));

union H8 { __half2 h2[4]; float4 f4; };

__global__ __launch_bounds__(256) void count_kernel(const int* __restrict__ col,
                                                    int* __restrict__ counts, int e) {
  int i = blockIdx.x * 256 + threadIdx.x;
  if (i < e) atomicAdd(&counts[col[i]], 1);
}

// Per-block partial sums of counts (250 elems/block) + dis = rsqrt(deg+1)
__global__ __launch_bounds__(256) void blocksum_dis_kernel(const int* __restrict__ counts,
                                                           float* __restrict__ dis,
                                                           int* __restrict__ blocksums) {
  __shared__ int red[4];
  int b = blockIdx.x, t = threadIdx.x;
  int i = b * SCAN_CHUNK + t;
  int c = 0;
  if (t < SCAN_CHUNK) {
    c = counts[i];
    dis[i] = rsqrtf((float)(c + 1));  // +1 self-loop => deg >= 1 always
  }
  int s = c;
#pragma unroll
  for (int off = 32; off > 0; off >>= 1) s += __shfl_down(s, off, 64);
  if ((t & 63) == 0) red[t >> 6] = s;
  __syncthreads();
  if (t == 0) blocksums[b] = red[0] + red[1] + red[2] + red[3];
}

// Each block: scan the 200 blocksums in LDS for its exclusive base, then
// scan its own 250 counts and write exclusive offsets.
__global__ __launch_bounds__(256) void offsets_kernel(const int* __restrict__ counts,
                                                      const int* __restrict__ blocksums,
                                                      int* __restrict__ offsets) {
  __shared__ int sb[256];
  __shared__ int loc[256];
  int b = blockIdx.x, t = threadIdx.x;
  sb[t] = (t < SCAN_BLOCKS) ? blocksums[t] : 0;
  __syncthreads();
#pragma unroll
  for (int off = 1; off < 256; off <<= 1) {
    int v = (t >= off) ? sb[t - off] : 0;
    __syncthreads();
    sb[t] += v;
    __syncthreads();
  }
  int base = (b == 0) ? 0 : sb[b - 1];
  int i = b * SCAN_CHUNK + t;
  int c = (t < SCAN_CHUNK) ? counts[i] : 0;
  loc[t] = c;
  __syncthreads();
#pragma unroll
  for (int off = 1; off < 256; off <<= 1) {
    int v = (t >= off) ? loc[t - off] : 0;
    __syncthreads();
    loc[t] += v;
    __syncthreads();
  }
  if (t < SCAN_CHUNK) offsets[i] = base + loc[t] - c;  // exclusive
  if (b == SCAN_BLOCKS - 1 && t == SCAN_CHUNK - 1) offsets[N_NODES] = base + loc[t];
}

__global__ __launch_bounds__(256) void fill_kernel(const int* __restrict__ row,
                                                   const int* __restrict__ col,
                                                   const int* __restrict__ offsets,
                                                   int* __restrict__ fillcnt,
                                                   int* __restrict__ srcidx, int e) {
  int i = blockIdx.x * 256 + threadIdx.x;
  if (i < e) {
    int c = col[i];
    int pos = offsets[c] + atomicAdd(&fillcnt[c], 1);
    srcidx[pos] = row[i];
  }
}

// MFMA GEMM, M=50000, K=128, 128 output cols. Block = 4 waves = 64 rows.
// Wave: 16 rows x 128 cols = 8 col-tiles(16) x 4 K-chunks(32) = 32 MFMA.
// W staged once in LDS transposed fp16: WT[n*WT_S + k]; b-frag = 8 contiguous
// halves (ds_read_b128, even bank distribution with stride 136).
// SPLIT=false (gemm1): A = fp32 X, out = fp16 Yh[r][c] = dis[r]*(X@Wa)[r][c]
// SPLIT=true  (gemm2): A = fp16 Xh, cols [Wa|Wb], out fp32:
//                      Yf[r*64+c]=..+ba[c] (mu), Yf[MU+r*64+c]=..+bb[c]
template <bool SPLIT>
__global__ __launch_bounds__(256) void gemm_mfma_kernel(const float* __restrict__ X,
                                                        const _Float16* __restrict__ Xh,
                                                        const float* __restrict__ Wa,
                                                        const float* __restrict__ Wb,
                                                        const float* __restrict__ dis,
                                                        const float* __restrict__ ba,
                                                        const float* __restrict__ bb,
                                                        _Float16* __restrict__ Yh,
                                                        float* __restrict__ Yf) {
  __shared__ _Float16 WT[128 * WT_S];  // 34 KB

  int t = threadIdx.x;
  // stage W transposed (fp32 -> fp16)
  for (int idx = t; idx < 128 * 128; idx += 256) {
    int k = idx >> 7, n = idx & 127;
    float w;
    if (!SPLIT) {
      w = Wa[k * 128 + n];
    } else {
      w = (n < 64) ? Wa[k * 64 + n] : Wb[k * 64 + (n - 64)];
    }
    WT[n * WT_S + k] = (_Float16)w;
  }
  __syncthreads();

  int wid = t >> 6, lane = t & 63;
  int q = lane >> 4, m = lane & 15;
  int r0 = blockIdx.x * 64 + wid * 16;

  // A fragments: lane covers row r0+m, k = 32c + 8q + j
  size_t ar = (size_t)min(r0 + m, N_NODES - 1);
  half8 afrag[4];
  if (!SPLIT) {
#pragma unroll
    for (int c = 0; c < 4; ++c) {
      const float* ap = &X[ar * 128 + 32 * c + 8 * q];
      float4 a0 = *(const float4*)ap;
      float4 a1 = *(const float4*)(ap + 4);
      half8 af = {(_Float16)a0.x, (_Float16)a0.y, (_Float16)a0.z, (_Float16)a0.w,
                  (_Float16)a1.x, (_Float16)a1.y, (_Float16)a1.z, (_Float16)a1.w};
      afrag[c] = af;
    }
  } else {
#pragma unroll
    for (int c = 0; c < 4; ++c) {
      afrag[c] = *(const half8*)&Xh[ar * 128 + 32 * c + 8 * q];
    }
  }

  // output rows for this lane: r0 + 4q + reg
  int orow[4];
  float dv[4];
#pragma unroll
  for (int g = 0; g < 4; ++g) {
    orow[g] = r0 + 4 * q + g;
    if (!SPLIT) dv[g] = dis[min(orow[g], N_NODES - 1)];
  }

#pragma unroll
  for (int n = 0; n < 8; ++n) {  // col tile: cols 16n + m
    floatx4 acc = {0.f, 0.f, 0.f, 0.f};
#pragma unroll
    for (int c = 0; c < 4; ++c) {
      half8 bfrag = *(const half8*)&WT[(16 * n + m) * WT_S + 32 * c + 8 * q];
      acc = __builtin_amdgcn_mfma_f32_16x16x32_f16(afrag[c], bfrag, acc, 0, 0, 0);
    }
    int colg = 16 * n + m;
    if (!SPLIT) {
#pragma unroll
      for (int g = 0; g < 4; ++g) {
        if (orow[g] < N_NODES)
          Yh[(size_t)orow[g] * 128 + colg] = (_Float16)(acc[g] * dv[g]);
      }
    } else {
      float bias = (colg < 64) ? ba[colg] : bb[colg - 64];
      size_t obase = (colg < 64) ? (size_t)colg : (size_t)MU_SIZE + (colg - 64);
#pragma unroll
      for (int g = 0; g < 4; ++g) {
        if (orow[g] < N_NODES)
          Yf[obase + (size_t)orow[g] * 64] = acc[g] + bias;
      }
    }
  }
}

// Input rows fp16, pre-scaled: Hs[i] = fp16(dis[i] * H[i]). fp32 accumulate.
// BIAS_RELU=true:  out[i] = fp16( di * relu(di*(sum Hs[r] + Hs[i]) + b) )
// BIAS_RELU=false: out[i] = fp16( di * (sum Hs[r] + Hs[i]) )
// One wave per node; quarter-wave (16 lanes x float4 = 8 halves) covers a
// 256B row; 4 edge slots/wave, unrolled x2 -> 8 gathers in flight.
template <bool BIAS_RELU>
__global__ __launch_bounds__(256) void aggregate_kernel(const __half* __restrict__ Hs,
                                                        const int* __restrict__ offsets,
                                                        const int* __restrict__ srcidx,
                                                        const float* __restrict__ dis,
                                                        const float* __restrict__ bias,
                                                        __half* __restrict__ outH, int n) {
  int wid = threadIdx.x >> 6, lane = threadIdx.x & 63;
  int q = lane >> 4, ql = lane & 15;
  int i = blockIdx.x * 4 + wid;
  if (i >= n) return;
  float di = dis[i];
  float4 selfv = ((const float4*)(Hs + (size_t)i * 128))[ql];
  float acc[8] = {0.f, 0.f, 0.f, 0.f, 0.f, 0.f, 0.f, 0.f};
  int beg = offsets[i], end = offsets[i + 1];
  int k = beg + q;  // quarter q owns slots beg+q, beg+q+4, ...
  for (; k + 4 < end; k += 8) {  // 2 edges per quarter per iter
    int r0 = srcidx[k];
    int r1 = srcidx[k + 4];
    float4 v0 = ((const float4*)(Hs + (size_t)r0 * 128))[ql];
    float4 v1 = ((const float4*)(Hs + (size_t)r1 * 128))[ql];
    const __half2* a0 = (const __half2*)&v0;
    const __half2* a1 = (const __half2*)&v1;
#pragma unroll
    for (int j = 0; j < 4; ++j) {
      float2 f0 = __half22float2(a0[j]);
      float2 f1 = __half22float2(a1[j]);
      acc[2 * j] += f0.x + f1.x;
      acc[2 * j + 1] += f0.y + f1.y;
    }
  }
  if (k < end) {
    int r0 = srcidx[k];
    float4 v0 = ((const float4*)(Hs + (size_t)r0 * 128))[ql];
    const __half2* a0 = (const __half2*)&v0;
#pragma unroll
    for (int j = 0; j < 4; ++j) {
      float2 f0 = __half22float2(a0[j]);
      acc[2 * j] += f0.x;
      acc[2 * j + 1] += f0.y;
    }
  }
  // combine the four quarters
#pragma unroll
  for (int j = 0; j < 8; ++j) {
    acc[j] += __shfl(acc[j], lane ^ 16, 64);
    acc[j] += __shfl(acc[j], lane ^ 32, 64);
  }
  if (q == 0) {
    const __half2* sh = (const __half2*)&selfv;
    float s[8];
#pragma unroll
    for (int j = 0; j < 4; ++j) {
      float2 f = __half22float2(sh[j]);
      s[2 * j] = di * (acc[2 * j] + f.x);
      s[2 * j + 1] = di * (acc[2 * j + 1] + f.y);
    }
    H8 u;
    if (BIAS_RELU) {
      float4 b0 = ((const float4*)bias)[2 * ql];
      float4 b1 = ((const float4*)bias)[2 * ql + 1];
      u.h2[0] = __float22half2_rn(
          make_float2(di * fmaxf(s[0] + b0.x, 0.f), di * fmaxf(s[1] + b0.y, 0.f)));
      u.h2[1] = __float22half2_rn(
          make_float2(di * fmaxf(s[2] + b0.z, 0.f), di * fmaxf(s[3] + b0.w, 0.f)));
      u.h2[2] = __float22half2_rn(
          make_float2(di * fmaxf(s[4] + b1.x, 0.f), di * fmaxf(s[5] + b1.y, 0.f)));
      u.h2[3] = __float22half2_rn(
          make_float2(di * fmaxf(s[6] + b1.z, 0.f), di * fmaxf(s[7] + b1.w, 0.f)));
    } else {
      u.h2[0] = __float22half2_rn(make_float2(s[0], s[1]));
      u.h2[1] = __float22half2_rn(make_float2(s[2], s[3]));
      u.h2[2] = __float22half2_rn(make_float2(s[4], s[5]));
      u.h2[3] = __float22half2_rn(make_float2(s[6], s[7]));
    }
    ((float4*)(outH + (size_t)i * 128))[ql] = u.f4;
  }
}

extern "C" void kernel_launch(void* const* d_in, const int* in_sizes, int n_in,
                              void* d_out, int out_size, void* d_ws, size_t ws_size,
                              hipStream_t stream) {
  const float* x = (const float*)d_in[0];
  const int* ei = (const int*)d_in[1];  // [2][E] int32: row=src, col=dst
  const float* W1 = (const float*)d_in[2];
  const float* b1 = (const float*)d_in[3];
  const float* Wmu = (const float*)d_in[4];
  const float* bmu = (const float*)d_in[5];
  const float* Wls = (const float*)d_in[6];
  const float* bls = (const float*)d_in[7];
  float* out = (float*)d_out;

  const int* row = ei;
  const int* col = ei + N_EDGES;

  // workspace layout (~42 MB)
  __half* bufAh = (__half*)d_ws;               // 6.4M f16 (gemm1 out, agg1 in)
  __half* bufBh = bufAh + 6400000;             // 6.4M f16 (agg1 out, agg2 in)
  __half* bufCh = bufBh + 6400000;             // 6.4M f16 (agg2 out, gemm2 in)
  float* dis = (float*)(bufCh + 6400000);      // 50000 f32
  int* counts = (int*)(dis + N_NODES);         // 50000 i32
  int* fillcnt = counts + N_NODES;             // 50000 i32
  int* offsets = fillcnt + N_NODES;            // 50001 i32
  int* srcidx = offsets + N_NODES + 1;         // 600000 i32
  int* blocksums = srcidx + N_EDGES;           // 200 i32

  hipMemsetAsync(counts, 0, 2 * N_NODES * sizeof(int), stream);  // counts + fillcnt

  int eb = (N_EDGES + 255) / 256;
  count_kernel<<<eb, 256, 0, stream>>>(col, counts, N_EDGES);
  blocksum_dis_kernel<<<SCAN_BLOCKS, 256, 0, stream>>>(counts, dis, blocksums);
  offsets_kernel<<<SCAN_BLOCKS, 256, 0, stream>>>(counts, blocksums, offsets);
  fill_kernel<<<eb, 256, 0, stream>>>(row, col, offsets, fillcnt, srcidx, N_EDGES);

  int gb = (N_NODES + 63) / 64;  // 782
  gemm_mfma_kernel<false><<<gb, 256, 0, stream>>>(x, nullptr, W1, nullptr, dis, nullptr,
                                                  nullptr, (_Float16*)bufAh, nullptr);
  aggregate_kernel<true><<<N_NODES / 4, 256, 0, stream>>>(bufAh, offsets, srcidx, dis, b1,
                                                          bufBh, N_NODES);
  aggregate_kernel<false><<<N_NODES / 4, 256, 0, stream>>>(bufBh, offsets, srcidx, dis,
                                                           nullptr, bufCh, N_NODES);
  gemm_mfma_kernel<true><<<gb, 256, 0, stream>>>(nullptr, (const _Float16*)bufCh, Wmu, Wls,
                                                 nullptr, bmu, bls, nullptr, out);
}

// Round 7
// 221.639 us; speedup vs baseline: 1.9972x; 1.0398x over previous
//
#include <hip/hip_runtime.h>
#include <hip/hip_fp16.h>

// VariationalGCNEncoder: N=50000 nodes, E=600000 edges, 128->128(relu)->2x64
// out = mu (50000x64) then logstd (50000x64), flat concat.
//
// R1: hierarchical scan (78us -> ~5us).
// R2: aggregate latency fix: float4 gather, half-wave/edge, dis pre-scaling.
// R3: LDS-tile VALU GEMM. R4: fp16 aggregation operand (row=256B).
// R5: MFMA fp16 GEMM (v_mfma_f32_16x16x32_f16).
// R6: (a) W^T prepared once in global fp16 by prep_wt -> GEMM staging is
//     coalesced + conflict-free (was 8-way ds_write_b16 conflict);
//     (b) MFMA operands swapped: A=W^T (LDS), B=X^T (k-contiguous -> direct
//     b128 global loads); D gives 4 consecutive feats/lane -> vector stores;
//     (c) grid-stride 512 blocks amortize W staging;
//     (d) aggregate: quarter-wave per node, no shuffles, unroll-4.

#define N_NODES 50000
#define N_EDGES 600000
#define MU_SIZE (N_NODES * 64)
#define SCAN_BLOCKS 200
#define SCAN_CHUNK 250  // SCAN_BLOCKS * SCAN_CHUNK == N_NODES
#define WT_S 136        // LDS row stride (halves), 272B: 16B-aligned rows

typedef _Float16 half8 __attribute__((ext_vector_type(8)));
typedef _Float16 half4 __attribute__((ext_vector_type(4)));
typedef float floatx4 __attribute__((ext_vector_type(4)));

union H8 { __half2 h2[4]; float4 f4; };

__global__ __launch_bounds__(256) void count_kernel(const int* __restrict__ col,
                                                    int* __restrict__ counts, int e) {
  int i = blockIdx.x * 256 + threadIdx.x;
  if (i < e) atomicAdd(&counts[col[i]], 1);
}

// Per-block partial sums of counts (250 elems/block) + dis = rsqrt(deg+1)
__global__ __launch_bounds__(256) void blocksum_dis_kernel(const int* __restrict__ counts,
                                                           float* __restrict__ dis,
                                                           int* __restrict__ blocksums) {
  __shared__ int red[4];
  int b = blockIdx.x, t = threadIdx.x;
  int i = b * SCAN_CHUNK + t;
  int c = 0;
  if (t < SCAN_CHUNK) {
    c = counts[i];
    dis[i] = rsqrtf((float)(c + 1));  // +1 self-loop => deg >= 1 always
  }
  int s = c;
#pragma unroll
  for (int off = 32; off > 0; off >>= 1) s += __shfl_down(s, off, 64);
  if ((t & 63) == 0) red[t >> 6] = s;
  __syncthreads();
  if (t == 0) blocksums[b] = red[0] + red[1] + red[2] + red[3];
}

// Each block: scan the 200 blocksums in LDS for its exclusive base, then
// scan its own 250 counts and write exclusive offsets.
__global__ __launch_bounds__(256) void offsets_kernel(const int* __restrict__ counts,
                                                      const int* __restrict__ blocksums,
                                                      int* __restrict__ offsets) {
  __shared__ int sb[256];
  __shared__ int loc[256];
  int b = blockIdx.x, t = threadIdx.x;
  sb[t] = (t < SCAN_BLOCKS) ? blocksums[t] : 0;
  __syncthreads();
#pragma unroll
  for (int off = 1; off < 256; off <<= 1) {
    int v = (t >= off) ? sb[t - off] : 0;
    __syncthreads();
    sb[t] += v;
    __syncthreads();
  }
  int base = (b == 0) ? 0 : sb[b - 1];
  int i = b * SCAN_CHUNK + t;
  int c = (t < SCAN_CHUNK) ? counts[i] : 0;
  loc[t] = c;
  __syncthreads();
#pragma unroll
  for (int off = 1; off < 256; off <<= 1) {
    int v = (t >= off) ? loc[t - off] : 0;
    __syncthreads();
    loc[t] += v;
    __syncthreads();
  }
  if (t < SCAN_CHUNK) offsets[i] = base + loc[t] - c;  // exclusive
  if (b == SCAN_BLOCKS - 1 && t == SCAN_CHUNK - 1) offsets[N_NODES] = base + loc[t];
}

__global__ __launch_bounds__(256) void fill_kernel(const int* __restrict__ row,
                                                   const int* __restrict__ col,
                                                   const int* __restrict__ offsets,
                                                   int* __restrict__ fillcnt,
                                                   int* __restrict__ srcidx, int e) {
  int i = blockIdx.x * 256 + threadIdx.x;
  if (i < e) {
    int c = col[i];
    int pos = offsets[c] + atomicAdd(&fillcnt[c], 1);
    srcidx[pos] = row[i];
  }
}

// Build fp16 transposed weights in global once:
// W1T[n][k] = fp16(W1[k][n]); W2T[n][k] = fp16(n<64 ? Wmu[k][n] : Wls[k][n-64])
__global__ __launch_bounds__(256) void prep_wt_kernel(const float* __restrict__ W1,
                                                      const float* __restrict__ Wmu,
                                                      const float* __restrict__ Wls,
                                                      _Float16* __restrict__ W1T,
                                                      _Float16* __restrict__ W2T) {
  int idx = blockIdx.x * 256 + threadIdx.x;  // grid 128 -> 32768
  int e = idx & 16383;
  int n = e >> 7, k = e & 127;
  if (idx < 16384) {
    W1T[e] = (_Float16)W1[k * 128 + n];
  } else {
    float w = (n < 64) ? Wmu[k * 64 + n] : Wls[k * 64 + (n - 64)];
    W2T[e] = (_Float16)w;
  }
}

// MFMA GEMM, M=50000 nodes, K=128, 128 output feats. Block = 4 waves;
// each wave-iteration covers 16 nodes x 128 feats.
// Operands swapped vs usual: A = W^T tile (16 feats x 32 k, from LDS),
// B = X^T (32 k x 16 nodes; k-contiguous == X row-major -> direct b128).
// D: lane(q,m) -> node m, feats 16f+4q..+3 (consecutive -> vector stores).
// SPLIT=false (gemm1): B from fp32 X (cvt), out fp16 Yh = dis[node]*(X@W1)
// SPLIT=true  (gemm2): B from fp16 Xh, out fp32 mu/logstd split + bias.
template <bool SPLIT>
__global__ __launch_bounds__(256) void gemm_mfma_kernel(const float* __restrict__ X,
                                                        const _Float16* __restrict__ Xh,
                                                        const _Float16* __restrict__ WT,
                                                        const float* __restrict__ dis,
                                                        const float* __restrict__ ba,
                                                        const float* __restrict__ bb,
                                                        _Float16* __restrict__ Yh,
                                                        float* __restrict__ Yf) {
  __shared__ _Float16 WL[128 * WT_S];  // 34 KB

  int t = threadIdx.x;
  // stage W^T: coalesced b128 global reads, conflict-free LDS writes
  for (int idx = t; idx < 128 * 16; idx += 256) {
    int n = idx >> 4, kk = (idx & 15) * 8;
    *(half8*)&WL[n * WT_S + kk] = *(const half8*)&WT[n * 128 + kk];
  }
  __syncthreads();

  int wid = t >> 6, lane = t & 63;
  int q = lane >> 4, m = lane & 15;
  const int ngroups = (N_NODES + 63) / 64;  // 782

  for (int g64 = blockIdx.x; g64 < ngroups; g64 += gridDim.x) {
    int node = g64 * 64 + wid * 16 + m;
    size_t nr = (size_t)min(node, N_NODES - 1);
    bool valid = node < N_NODES;

    // B fragments: lane (q,m) holds X[node][32c + 8q + j], j=0..7
    half8 xfrag[4];
    if (!SPLIT) {
#pragma unroll
      for (int c = 0; c < 4; ++c) {
        const float* ap = &X[nr * 128 + 32 * c + 8 * q];
        float4 a0 = *(const float4*)ap;
        float4 a1 = *(const float4*)(ap + 4);
        half8 af = {(_Float16)a0.x, (_Float16)a0.y, (_Float16)a0.z, (_Float16)a0.w,
                    (_Float16)a1.x, (_Float16)a1.y, (_Float16)a1.z, (_Float16)a1.w};
        xfrag[c] = af;
      }
    } else {
#pragma unroll
      for (int c = 0; c < 4; ++c) {
        xfrag[c] = *(const half8*)&Xh[nr * 128 + 32 * c + 8 * q];
      }
    }
    float dnode = SPLIT ? 0.f : dis[nr];

#pragma unroll
    for (int f = 0; f < 8; ++f) {  // feat tile: feats 16f..16f+15
      floatx4 acc = {0.f, 0.f, 0.f, 0.f};
#pragma unroll
      for (int c = 0; c < 4; ++c) {
        half8 wfrag = *(const half8*)&WL[(16 * f + m) * WT_S + 32 * c + 8 * q];
        acc = __builtin_amdgcn_mfma_f32_16x16x32_f16(wfrag, xfrag[c], acc, 0, 0, 0);
      }
      int fbase = 16 * f + 4 * q;  // 4 consecutive feats for this lane
      if (!SPLIT) {
        if (valid) {
          half4 o = {(_Float16)(acc[0] * dnode), (_Float16)(acc[1] * dnode),
                     (_Float16)(acc[2] * dnode), (_Float16)(acc[3] * dnode)};
          *(half4*)&Yh[(size_t)node * 128 + fbase] = o;
        }
      } else {
        // f<4 -> mu cols (fbase<64), f>=4 -> logstd (wave-uniform branch)
        float4 bias = (f < 4) ? *(const float4*)&ba[fbase]
                              : *(const float4*)&bb[fbase - 64];
        float4 o = make_float4(acc[0] + bias.x, acc[1] + bias.y, acc[2] + bias.z,
                               acc[3] + bias.w);
        if (valid) {
          if (f < 4)
            *(float4*)&Yf[(size_t)node * 64 + fbase] = o;
          else
            *(float4*)&Yf[MU_SIZE + (size_t)node * 64 + (fbase - 64)] = o;
        }
      }
    }
  }
}

// Input rows fp16, pre-scaled: Hs[i] = fp16(dis[i] * H[i]). fp32 accumulate.
// One quarter-wave (16 lanes x float4-of-halves) per node; no cross-lane
// reduce; edge loop unrolled x4 -> 16 gathers in flight per wave.
// BIAS_RELU=true:  out[i] = fp16( di * relu(di*(sum Hs[r] + Hs[i]) + b) )
// BIAS_RELU=false: out[i] = fp16( di * (sum Hs[r] + Hs[i]) )
template <bool BIAS_RELU>
__global__ __launch_bounds__(256) void aggregate_kernel(const __half* __restrict__ Hs,
                                                        const int* __restrict__ offsets,
                                                        const int* __restrict__ srcidx,
                                                        const float* __restrict__ dis,
                                                        const float* __restrict__ bias,
                                                        __half* __restrict__ outH, int n) {
  int wid = threadIdx.x >> 6, lane = threadIdx.x & 63;
  int q = lane >> 4, ql = lane & 15;
  int i = blockIdx.x * 16 + wid * 4 + q;
  if (i >= n) return;
  float di = dis[i];
  float4 selfv = ((const float4*)(Hs + (size_t)i * 128))[ql];
  float acc[8] = {0.f, 0.f, 0.f, 0.f, 0.f, 0.f, 0.f, 0.f};
  int k = offsets[i], end = offsets[i + 1];
  for (; k + 3 < end; k += 4) {
    int r0 = srcidx[k];
    int r1 = srcidx[k + 1];
    int r2 = srcidx[k + 2];
    int r3 = srcidx[k + 3];
    float4 v0 = ((const float4*)(Hs + (size_t)r0 * 128))[ql];
    float4 v1 = ((const float4*)(Hs + (size_t)r1 * 128))[ql];
    float4 v2 = ((const float4*)(Hs + (size_t)r2 * 128))[ql];
    float4 v3 = ((const float4*)(Hs + (size_t)r3 * 128))[ql];
    const __half2* a0 = (const __half2*)&v0;
    const __half2* a1 = (const __half2*)&v1;
    const __half2* a2 = (const __half2*)&v2;
    const __half2* a3 = (const __half2*)&v3;
#pragma unroll
    for (int j = 0; j < 4; ++j) {
      float2 f0 = __half22float2(a0[j]);
      float2 f1 = __half22float2(a1[j]);
      float2 f2 = __half22float2(a2[j]);
      float2 f3 = __half22float2(a3[j]);
      acc[2 * j] += (f0.x + f1.x) + (f2.x + f3.x);
      acc[2 * j + 1] += (f0.y + f1.y) + (f2.y + f3.y);
    }
  }
  for (; k < end; ++k) {
    int r0 = srcidx[k];
    float4 v0 = ((const float4*)(Hs + (size_t)r0 * 128))[ql];
    const __half2* a0 = (const __half2*)&v0;
#pragma unroll
    for (int j = 0; j < 4; ++j) {
      float2 f0 = __half22float2(a0[j]);
      acc[2 * j] += f0.x;
      acc[2 * j + 1] += f0.y;
    }
  }
  const __half2* sh = (const __half2*)&selfv;
  float s[8];
#pragma unroll
  for (int j = 0; j < 4; ++j) {
    float2 f = __half22float2(sh[j]);
    s[2 * j] = di * (acc[2 * j] + f.x);
    s[2 * j + 1] = di * (acc[2 * j + 1] + f.y);
  }
  H8 u;
  if (BIAS_RELU) {
    float4 b0 = ((const float4*)bias)[2 * ql];
    float4 b1 = ((const float4*)bias)[2 * ql + 1];
    u.h2[0] = __float22half2_rn(
        make_float2(di * fmaxf(s[0] + b0.x, 0.f), di * fmaxf(s[1] + b0.y, 0.f)));
    u.h2[1] = __float22half2_rn(
        make_float2(di * fmaxf(s[2] + b0.z, 0.f), di * fmaxf(s[3] + b0.w, 0.f)));
    u.h2[2] = __float22half2_rn(
        make_float2(di * fmaxf(s[4] + b1.x, 0.f), di * fmaxf(s[5] + b1.y, 0.f)));
    u.h2[3] = __float22half2_rn(
        make_float2(di * fmaxf(s[6] + b1.z, 0.f), di * fmaxf(s[7] + b1.w, 0.f)));
  } else {
    u.h2[0] = __float22half2_rn(make_float2(s[0], s[1]));
    u.h2[1] = __float22half2_rn(make_float2(s[2], s[3]));
    u.h2[2] = __float22half2_rn(make_float2(s[4], s[5]));
    u.h2[3] = __float22half2_rn(make_float2(s[6], s[7]));
  }
  ((float4*)(outH + (size_t)i * 128))[ql] = u.f4;
}

extern "C" void kernel_launch(void* const* d_in, const int* in_sizes, int n_in,
                              void* d_out, int out_size, void* d_ws, size_t ws_size,
                              hipStream_t stream) {
  const float* x = (const float*)d_in[0];
  const int* ei = (const int*)d_in[1];  // [2][E] int32: row=src, col=dst
  const float* W1 = (const float*)d_in[2];
  const float* b1 = (const float*)d_in[3];
  const float* Wmu = (const float*)d_in[4];
  const float* bmu = (const float*)d_in[5];
  const float* Wls = (const float*)d_in[6];
  const float* bls = (const float*)d_in[7];
  float* out = (float*)d_out;

  const int* row = ei;
  const int* col = ei + N_EDGES;

  // workspace layout (~42 MB)
  __half* bufAh = (__half*)d_ws;               // 6.4M f16 (gemm1 out, agg1 in)
  __half* bufBh = bufAh + 6400000;             // 6.4M f16 (agg1 out, agg2 in)
  __half* bufCh = bufBh + 6400000;             // 6.4M f16 (agg2 out, gemm2 in)
  float* dis = (float*)(bufCh + 6400000);      // 50000 f32
  int* counts = (int*)(dis + N_NODES);         // 50000 i32
  int* fillcnt = counts + N_NODES;             // 50000 i32
  int* offsets = fillcnt + N_NODES;            // 50001 i32
  int* srcidx = offsets + N_NODES + 1;         // 600000 i32
  int* blocksums = srcidx + N_EDGES;           // 200 i32
  _Float16* W1T = (_Float16*)(blocksums + 256);  // 16384 f16
  _Float16* W2T = W1T + 16384;                   // 16384 f16

  hipMemsetAsync(counts, 0, 2 * N_NODES * sizeof(int), stream);  // counts + fillcnt

  prep_wt_kernel<<<128, 256, 0, stream>>>(W1, Wmu, Wls, W1T, W2T);

  int eb = (N_EDGES + 255) / 256;
  count_kernel<<<eb, 256, 0, stream>>>(col, counts, N_EDGES);
  blocksum_dis_kernel<<<SCAN_BLOCKS, 256, 0, stream>>>(counts, dis, blocksums);
  offsets_kernel<<<SCAN_BLOCKS, 256, 0, stream>>>(counts, blocksums, offsets);
  fill_kernel<<<eb, 256, 0, stream>>>(row, col, offsets, fillcnt, srcidx, N_EDGES);

  gemm_mfma_kernel<false><<<512, 256, 0, stream>>>(x, nullptr, W1T, dis, nullptr, nullptr,
                                                   (_Float16*)bufAh, nullptr);
  int ab = (N_NODES + 15) / 16;  // 3125
  aggregate_kernel<true><<<ab, 256, 0, stream>>>(bufAh, offsets, srcidx, dis, b1,
                                                 bufBh, N_NODES);
  aggregate_kernel<false><<<ab, 256, 0, stream>>>(bufBh, offsets, srcidx, dis,
                                                  nullptr, bufCh, N_NODES);
  gemm_mfma_kernel<true><<<512, 256, 0, stream>>>(nullptr, (const _Float16*)bufCh, W2T,
                                                  nullptr, bmu, bls, nullptr, out);
}